// Round 9
// baseline (329.939 us; speedup 1.0000x reference)
//
#include <hip/hip_runtime.h>

#define NN 50000
#define NE 800000
#define DIN 128
#define HD 128
#define CD 64
#define NCHUNK ((NN + 1023) / 1024)  // 49

// ---------------- CSR build ----------------
__global__ void count_deg(const int* __restrict__ dst, int* __restrict__ cnt) {
    int e = blockIdx.x * blockDim.x + threadIdx.x;
    if (e < NE) atomicAdd(&cnt[dst[e]], 1);
}

// chunk-local exclusive scan + chunk totals; also emits dinv = rsqrt(cnt+2)
__global__ void __launch_bounds__(1024) scan_a(int* __restrict__ cnt, int* __restrict__ sums,
                                               float* __restrict__ dinv) {
    __shared__ int wsum[16];
    int t = threadIdx.x;
    int i = blockIdx.x * 1024 + t;
    int v = (i < NN) ? cnt[i] : 0;
    if (i < NN) dinv[i] = rsqrtf((float)(v + 2));  // +2 self loops
    int x = v;
#pragma unroll
    for (int off = 1; off < 64; off <<= 1) {
        int y = __shfl_up(x, off, 64);
        if ((t & 63) >= off) x += y;
    }
    int wid = t >> 6;
    if ((t & 63) == 63) wsum[wid] = x;
    __syncthreads();
    if (t < 16) {
        int s = wsum[t];
#pragma unroll
        for (int off = 1; off < 16; off <<= 1) {
            int y = __shfl_up(s, off, 16);
            if (t >= off) s += y;
        }
        wsum[t] = s;
    }
    __syncthreads();
    int base = (wid > 0) ? wsum[wid - 1] : 0;
    int incl = base + x;
    if (i < NN) cnt[i] = incl - v;  // exclusive within chunk
    if (t == 1023) sums[blockIdx.x] = incl;
}

__global__ void scan_b(int* __restrict__ sums) {
    int t = threadIdx.x;
    int v = (t < NCHUNK) ? sums[t] : 0;
    int x = v;
#pragma unroll
    for (int off = 1; off < 64; off <<= 1) {
        int y = __shfl_up(x, off, 64);
        if (t >= off) x += y;
    }
    if (t < NCHUNK) sums[t] = x - v;  // exclusive chunk bases
}

__global__ void scan_c(int* __restrict__ cnt, const int* __restrict__ sums) {
    int i = blockIdx.x * blockDim.x + threadIdx.x;
    if (i < NN) cnt[i] += sums[i >> 10];
}

// after fill: rowptr[v] == end offset of row v (start is rowptr[v-1])
__global__ void fill_csr(const int* __restrict__ src, const int* __restrict__ dst,
                         int* __restrict__ rowptr, int* __restrict__ col) {
    int e = blockIdx.x * blockDim.x + threadIdx.x;
    if (e < NE) {
        int d = dst[e];
        int pos = atomicAdd(&rowptr[d], 1);
        col[pos] = src[e];
    }
}

// ---------------- GEMM1: hs1 = dinv * (x @ W1) ----------------
// W1 in LDS (64 KB). 512 threads = 8 waves; each wave 8 rows x 128 cols (float2/lane).
// x read as runtime-uniform global_load_dwordx4 (vmcnt-pipelined, NOT s_load:
// SMEM shares lgkmcnt with DS and returns out-of-order -> forced lgkmcnt(0) drains).
__global__ void __launch_bounds__(512, 4) gemm1(const float* __restrict__ x, const float* __restrict__ W1,
                                                const float* __restrict__ dinv, float* __restrict__ hs1) {
    __shared__ float w[DIN * HD];  // 64 KB
    int t = threadIdx.x;
    {
        float4* wv = (float4*)w;
        const float4* Wg = (const float4*)W1;
        for (int i = t; i < DIN * HD / 4; i += 512) wv[i] = Wg[i];
    }
    __syncthreads();
    int lane = t & 63;
    int wid = t >> 6;                       // compiler-divergent -> x loads stay vector
    int row0 = blockIdx.x * 64 + wid * 8;
    if (row0 > NN - 8) row0 = NN - 8;       // tail clamp: duplicate rows, identical values
    const float* xr = x + (size_t)row0 * DIN;

    float2 acc[8];
#pragma unroll
    for (int r = 0; r < 8; ++r) acc[r] = make_float2(0.f, 0.f);
    const float2* w2 = (const float2*)w;
#pragma unroll 2
    for (int k4 = 0; k4 < DIN / 4; ++k4) {
        float4 xv[8];
#pragma unroll
        for (int r = 0; r < 8; ++r) xv[r] = *(const float4*)(xr + r * DIN + k4 * 4);
        float2 wk[4];
#pragma unroll
        for (int j = 0; j < 4; ++j) wk[j] = w2[(k4 * 4 + j) * 64 + lane];
#pragma unroll
        for (int r = 0; r < 8; ++r) {
            acc[r].x += xv[r].x * wk[0].x; acc[r].y += xv[r].x * wk[0].y;
            acc[r].x += xv[r].y * wk[1].x; acc[r].y += xv[r].y * wk[1].y;
            acc[r].x += xv[r].z * wk[2].x; acc[r].y += xv[r].z * wk[2].y;
            acc[r].x += xv[r].w * wk[3].x; acc[r].y += xv[r].w * wk[3].y;
        }
    }
    float2* O = (float2*)hs1;
#pragma unroll
    for (int r = 0; r < 8; ++r) {
        float di = dinv[row0 + r];
        float2 o;
        o.x = acc[r].x * di;
        o.y = acc[r].y * di;
        O[(size_t)(row0 + r) * 64 + lane] = o;
    }
}

// ---------------- GEMM2: hs2 = dinv * (h1 @ W2) ----------------
// W2 in LDS (32 KB). 512 threads = 8 waves; each wave 8 rows x 64 cols.
__global__ void __launch_bounds__(512, 4) gemm2(const float* __restrict__ h1, const float* __restrict__ W2,
                                                const float* __restrict__ dinv, float* __restrict__ hs2) {
    __shared__ float w[DIN * CD];  // 32 KB
    int t = threadIdx.x;
    {
        float4* wv = (float4*)w;
        const float4* Wg = (const float4*)W2;
        for (int i = t; i < DIN * CD / 4; i += 512) wv[i] = Wg[i];
    }
    __syncthreads();
    int lane = t & 63;
    int wid = t >> 6;
    int row0 = blockIdx.x * 64 + wid * 8;
    if (row0 > NN - 8) row0 = NN - 8;
    const float* xr = h1 + (size_t)row0 * DIN;

    float acc[8];
#pragma unroll
    for (int r = 0; r < 8; ++r) acc[r] = 0.f;
#pragma unroll 2
    for (int k4 = 0; k4 < DIN / 4; ++k4) {
        float4 xv[8];
#pragma unroll
        for (int r = 0; r < 8; ++r) xv[r] = *(const float4*)(xr + r * DIN + k4 * 4);
        float wk[4];
#pragma unroll
        for (int j = 0; j < 4; ++j) wk[j] = w[(k4 * 4 + j) * 64 + lane];
#pragma unroll
        for (int r = 0; r < 8; ++r) {
            acc[r] += xv[r].x * wk[0];
            acc[r] += xv[r].y * wk[1];
            acc[r] += xv[r].z * wk[2];
            acc[r] += xv[r].w * wk[3];
        }
    }
#pragma unroll
    for (int r = 0; r < 8; ++r)
        hs2[(size_t)(row0 + r) * CD + lane] = acc[r] * dinv[row0 + r];
}

// ---------------- agg1: CSR gather (float2/lane, one row per wave), unroll 8 ----------------
__global__ void agg1_csr(const int* __restrict__ rowptr, const int* __restrict__ col,
                         const float* __restrict__ hs1, const float* __restrict__ dinv,
                         const float* __restrict__ b1, float* __restrict__ h1) {
    int t = threadIdx.x;
    int v = blockIdx.x * 4 + (t >> 6);
    int c2 = t & 63;  // float2 lane
    const float2* H = (const float2*)hs1;  // row stride 64
    int start = (v == 0) ? 0 : rowptr[v - 1];
    int end = rowptr[v];
    float2 self = H[(size_t)v * 64 + c2];
    float ax = 2.f * self.x, ay = 2.f * self.y;
    int j = start;
    for (; j + 8 <= end; j += 8) {
        int s0 = col[j], s1 = col[j + 1], s2 = col[j + 2], s3 = col[j + 3];
        int s4 = col[j + 4], s5 = col[j + 5], s6 = col[j + 6], s7 = col[j + 7];
        float2 v0 = H[(size_t)s0 * 64 + c2];
        float2 v1 = H[(size_t)s1 * 64 + c2];
        float2 v2 = H[(size_t)s2 * 64 + c2];
        float2 v3 = H[(size_t)s3 * 64 + c2];
        float2 v4 = H[(size_t)s4 * 64 + c2];
        float2 v5 = H[(size_t)s5 * 64 + c2];
        float2 v6 = H[(size_t)s6 * 64 + c2];
        float2 v7 = H[(size_t)s7 * 64 + c2];
        ax += (v0.x + v1.x) + (v2.x + v3.x) + ((v4.x + v5.x) + (v6.x + v7.x));
        ay += (v0.y + v1.y) + (v2.y + v3.y) + ((v4.y + v5.y) + (v6.y + v7.y));
    }
    for (; j < end; ++j) {
        float2 u = H[(size_t)col[j] * 64 + c2];
        ax += u.x; ay += u.y;
    }
    float di = dinv[v];
    int c = c2 * 2;
    float2 r;
    r.x = fmaxf(di * ax + b1[c], 0.f);
    r.y = fmaxf(di * ay + b1[c + 1], 0.f);
    ((float2*)h1)[(size_t)v * 64 + c2] = r;
}

// ---------------- agg2: CSR gather + bias + log_softmax (one wave per row), unroll 8 ----------------
__global__ void agg2_csr(const int* __restrict__ rowptr, const int* __restrict__ col,
                         const float* __restrict__ hs2, const float* __restrict__ dinv,
                         const float* __restrict__ b2, float* __restrict__ out) {
    int t = threadIdx.x;
    int v = blockIdx.x * 4 + (t >> 6);
    int c = t & 63;
    int start = (v == 0) ? 0 : rowptr[v - 1];
    int end = rowptr[v];
    float acc = 2.f * hs2[(size_t)v * CD + c];
    int j = start;
    for (; j + 8 <= end; j += 8) {
        int s0 = col[j], s1 = col[j + 1], s2 = col[j + 2], s3 = col[j + 3];
        int s4 = col[j + 4], s5 = col[j + 5], s6 = col[j + 6], s7 = col[j + 7];
        float a0 = hs2[(size_t)s0 * CD + c], a1 = hs2[(size_t)s1 * CD + c];
        float a2 = hs2[(size_t)s2 * CD + c], a3 = hs2[(size_t)s3 * CD + c];
        float a4 = hs2[(size_t)s4 * CD + c], a5 = hs2[(size_t)s5 * CD + c];
        float a6 = hs2[(size_t)s6 * CD + c], a7 = hs2[(size_t)s7 * CD + c];
        acc += (a0 + a1) + (a2 + a3) + ((a4 + a5) + (a6 + a7));
    }
    for (; j < end; ++j) acc += hs2[(size_t)col[j] * CD + c];
    float o = dinv[v] * acc + b2[c];
    float m = o;
#pragma unroll
    for (int off = 32; off >= 1; off >>= 1) m = fmaxf(m, __shfl_xor(m, off, 64));
    float ex = __expf(o - m);
    float s = ex;
#pragma unroll
    for (int off = 32; off >= 1; off >>= 1) s += __shfl_xor(s, off, 64);
    out[(size_t)v * CD + c] = o - m - __logf(s);
}

extern "C" void kernel_launch(void* const* d_in, const int* in_sizes, int n_in,
                              void* d_out, int out_size, void* d_ws, size_t ws_size,
                              hipStream_t stream) {
    const float* x  = (const float*)d_in[0];
    const int*   ei = (const int*)d_in[1];   // [2, E] int32
    const float* W1 = (const float*)d_in[2];
    const float* b1 = (const float*)d_in[3];
    const float* W2 = (const float*)d_in[4];
    const float* b2 = (const float*)d_in[5];
    float* out = (float*)d_out;

    const int* src = ei;
    const int* dst = ei + NE;

    float* ws = (float*)d_ws;
    float* dinv   = ws;                        // NN floats
    int*   rowptr = (int*)(ws + 65536);        // NN ints
    int*   col    = (int*)(ws + 131072);       // NE ints
    int*   sums   = (int*)(ws + 931072);       // 64 ints
    float* hs1    = ws + 933888;               // NN*HD
    float* h1     = ws + 7333888;              // NN*HD
    float* hs2    = hs1;                       // reuse (hs1 dead after agg1)

    // ---- CSR build ----
    hipMemsetAsync(rowptr, 0, (size_t)NN * sizeof(int), stream);
    count_deg<<<(NE + 255) / 256, 256, 0, stream>>>(dst, rowptr);
    scan_a<<<NCHUNK, 1024, 0, stream>>>(rowptr, sums, dinv);
    scan_b<<<1, 64, 0, stream>>>(sums);
    scan_c<<<(NN + 255) / 256, 256, 0, stream>>>(rowptr, sums);
    fill_csr<<<(NE + 255) / 256, 256, 0, stream>>>(src, dst, rowptr, col);

    // ---- layer 1 ----
    gemm1<<<(NN + 63) / 64, 512, 0, stream>>>(x, W1, dinv, hs1);
    agg1_csr<<<NN / 4, 256, 0, stream>>>(rowptr, col, hs1, dinv, b1, h1);

    // ---- layer 2 ----
    gemm2<<<(NN + 63) / 64, 512, 0, stream>>>(h1, W2, dinv, hs2);
    agg2_csr<<<NN / 4, 256, 0, stream>>>(rowptr, col, hs2, dinv, b2, out);
}

// Round 10
// 256.466 us; speedup vs baseline: 1.2865x; 1.2865x over previous
//
#include <hip/hip_runtime.h>

#define NN 50000
#define NE 800000
#define DIN 128
#define HD 128
#define CD 64
#define NCHUNK ((NN + 1023) / 1024)  // 49
#define XSTR 132                     // padded x-tile row stride (floats), 16B-aligned, kills group conflicts

// ---------------- CSR build ----------------
__global__ void count_deg(const int* __restrict__ dst, int* __restrict__ cnt) {
    int e = blockIdx.x * blockDim.x + threadIdx.x;
    if (e < NE) atomicAdd(&cnt[dst[e]], 1);
}

// chunk-local exclusive scan + chunk totals; also emits dinv = rsqrt(cnt+2)
__global__ void __launch_bounds__(1024) scan_a(int* __restrict__ cnt, int* __restrict__ sums,
                                               float* __restrict__ dinv) {
    __shared__ int wsum[16];
    int t = threadIdx.x;
    int i = blockIdx.x * 1024 + t;
    int v = (i < NN) ? cnt[i] : 0;
    if (i < NN) dinv[i] = rsqrtf((float)(v + 2));  // +2 self loops
    int x = v;
#pragma unroll
    for (int off = 1; off < 64; off <<= 1) {
        int y = __shfl_up(x, off, 64);
        if ((t & 63) >= off) x += y;
    }
    int wid = t >> 6;
    if ((t & 63) == 63) wsum[wid] = x;
    __syncthreads();
    if (t < 16) {
        int s = wsum[t];
#pragma unroll
        for (int off = 1; off < 16; off <<= 1) {
            int y = __shfl_up(s, off, 16);
            if (t >= off) s += y;
        }
        wsum[t] = s;
    }
    __syncthreads();
    int base = (wid > 0) ? wsum[wid - 1] : 0;
    int incl = base + x;
    if (i < NN) cnt[i] = incl - v;  // exclusive within chunk
    if (t == 1023) sums[blockIdx.x] = incl;
}

__global__ void scan_b(int* __restrict__ sums) {
    int t = threadIdx.x;
    int v = (t < NCHUNK) ? sums[t] : 0;
    int x = v;
#pragma unroll
    for (int off = 1; off < 64; off <<= 1) {
        int y = __shfl_up(x, off, 64);
        if (t >= off) x += y;
    }
    if (t < NCHUNK) sums[t] = x - v;  // exclusive chunk bases
}

__global__ void scan_c(int* __restrict__ cnt, const int* __restrict__ sums) {
    int i = blockIdx.x * blockDim.x + threadIdx.x;
    if (i < NN) cnt[i] += sums[i >> 10];
}

// after fill: rowptr[v] == end offset of row v (start is rowptr[v-1])
__global__ void fill_csr(const int* __restrict__ src, const int* __restrict__ dst,
                         int* __restrict__ rowptr, int* __restrict__ col) {
    int e = blockIdx.x * blockDim.x + threadIdx.x;
    if (e < NE) {
        int d = dst[e];
        int pos = atomicAdd(&rowptr[d], 1);
        col[pos] = src[e];
    }
}

// ---------------- GEMM1: hs1 = dinv * (x @ W1) ----------------
// 256 threads / 4 waves / 64 rows per block. W1 (64KB) + padded x-tile (33.8KB) in LDS.
// Wave = 16 col-lanes x 4 row-groups; per lane acc[4 rows][8 cols] (cols {4cl, 64+4cl}).
// Per k-quad: 12 ds_read_b128 + 128 FMA -> VALU-bound.
__global__ void __launch_bounds__(256, 1) gemm1(const float* __restrict__ x, const float* __restrict__ W1,
                                                const float* __restrict__ dinv, float* __restrict__ hs1) {
    __shared__ float w[DIN * HD];     // [k][c] 64 KB
    __shared__ float xs[64 * XSTR];   // [r][k] padded, 33.8 KB
    int t = threadIdx.x;
    int row0 = blockIdx.x * 64;
    {
        const float4* Wg = (const float4*)W1;
        float4* wv = (float4*)w;
#pragma unroll
        for (int i = 0; i < 16; ++i) wv[t + 256 * i] = Wg[t + 256 * i];
    }
    {
#pragma unroll
        for (int i = 0; i < 8; ++i) {
            int m = t + 256 * i;
            int r = m >> 5, kq = m & 31;
            int gr = row0 + r; if (gr > NN - 1) gr = NN - 1;
            float4 v = ((const float4*)x)[(size_t)gr * 32 + kq];
            *(float4*)&xs[r * XSTR + 4 * kq] = v;
        }
    }
    __syncthreads();

    int lane = t & 63, wv_id = t >> 6;
    int cl = lane & 15, g = lane >> 4;
    int wrow = wv_id * 16 + g * 4;    // local row base (0..60)
    int ca = 4 * cl;                  // first col quad
    int cb = 64 + 4 * cl;             // second col quad

    float4 acc[4][2];
#pragma unroll
    for (int r = 0; r < 4; ++r) { acc[r][0] = make_float4(0,0,0,0); acc[r][1] = make_float4(0,0,0,0); }

#pragma unroll 2
    for (int kq = 0; kq < 32; ++kq) {
        float4 xv[4];
#pragma unroll
        for (int rr = 0; rr < 4; ++rr)
            xv[rr] = *(const float4*)&xs[(wrow + rr) * XSTR + 4 * kq];
#pragma unroll
        for (int j = 0; j < 4; ++j) {
            float4 wa = *(const float4*)&w[(4 * kq + j) * HD + ca];
            float4 wb = *(const float4*)&w[(4 * kq + j) * HD + cb];
#pragma unroll
            for (int rr = 0; rr < 4; ++rr) {
                float xj = (j == 0) ? xv[rr].x : (j == 1) ? xv[rr].y : (j == 2) ? xv[rr].z : xv[rr].w;
                acc[rr][0].x += xj * wa.x; acc[rr][0].y += xj * wa.y;
                acc[rr][0].z += xj * wa.z; acc[rr][0].w += xj * wa.w;
                acc[rr][1].x += xj * wb.x; acc[rr][1].y += xj * wb.y;
                acc[rr][1].z += xj * wb.z; acc[rr][1].w += xj * wb.w;
            }
        }
    }
#pragma unroll
    for (int rr = 0; rr < 4; ++rr) {
        int row = row0 + wrow + rr;
        if (row < NN) {
            float di = dinv[row];
            float4 oa = acc[rr][0], ob = acc[rr][1];
            oa.x *= di; oa.y *= di; oa.z *= di; oa.w *= di;
            ob.x *= di; ob.y *= di; ob.z *= di; ob.w *= di;
            *(float4*)&hs1[(size_t)row * HD + ca] = oa;
            *(float4*)&hs1[(size_t)row * HD + cb] = ob;
        }
    }
}

// ---------------- GEMM2: hs2 = dinv * (h1 @ W2) ----------------
// Same structure; W2 32KB + x-tile 33.8KB = 66KB -> 2 blocks/CU. acc[4 rows][4 cols].
__global__ void __launch_bounds__(256, 2) gemm2(const float* __restrict__ h1, const float* __restrict__ W2,
                                                const float* __restrict__ dinv, float* __restrict__ hs2) {
    __shared__ float w[DIN * CD];     // [k][c] 32 KB
    __shared__ float xs[64 * XSTR];   // 33.8 KB
    int t = threadIdx.x;
    int row0 = blockIdx.x * 64;
    {
        const float4* Wg = (const float4*)W2;
        float4* wv = (float4*)w;
#pragma unroll
        for (int i = 0; i < 8; ++i) wv[t + 256 * i] = Wg[t + 256 * i];
    }
    {
#pragma unroll
        for (int i = 0; i < 8; ++i) {
            int m = t + 256 * i;
            int r = m >> 5, kq = m & 31;
            int gr = row0 + r; if (gr > NN - 1) gr = NN - 1;
            float4 v = ((const float4*)h1)[(size_t)gr * 32 + kq];
            *(float4*)&xs[r * XSTR + 4 * kq] = v;
        }
    }
    __syncthreads();

    int lane = t & 63, wv_id = t >> 6;
    int cl = lane & 15, g = lane >> 4;
    int wrow = wv_id * 16 + g * 4;
    int ca = 4 * cl;

    float4 acc[4];
#pragma unroll
    for (int r = 0; r < 4; ++r) acc[r] = make_float4(0,0,0,0);

#pragma unroll 2
    for (int kq = 0; kq < 32; ++kq) {
        float4 xv[4];
#pragma unroll
        for (int rr = 0; rr < 4; ++rr)
            xv[rr] = *(const float4*)&xs[(wrow + rr) * XSTR + 4 * kq];
#pragma unroll
        for (int j = 0; j < 4; ++j) {
            float4 wa = *(const float4*)&w[(4 * kq + j) * CD + ca];
#pragma unroll
            for (int rr = 0; rr < 4; ++rr) {
                float xj = (j == 0) ? xv[rr].x : (j == 1) ? xv[rr].y : (j == 2) ? xv[rr].z : xv[rr].w;
                acc[rr].x += xj * wa.x; acc[rr].y += xj * wa.y;
                acc[rr].z += xj * wa.z; acc[rr].w += xj * wa.w;
            }
        }
    }
#pragma unroll
    for (int rr = 0; rr < 4; ++rr) {
        int row = row0 + wrow + rr;
        if (row < NN) {
            float di = dinv[row];
            float4 o = acc[rr];
            o.x *= di; o.y *= di; o.z *= di; o.w *= di;
            *(float4*)&hs2[(size_t)row * CD + ca] = o;
        }
    }
}

// ---------------- agg1: CSR gather (float2/lane, one row per wave), unroll 4 ----------------
__global__ void agg1_csr(const int* __restrict__ rowptr, const int* __restrict__ col,
                         const float* __restrict__ hs1, const float* __restrict__ dinv,
                         const float* __restrict__ b1, float* __restrict__ h1) {
    int t = threadIdx.x;
    int v = blockIdx.x * 4 + (t >> 6);
    int c2 = t & 63;  // float2 lane
    const float2* H = (const float2*)hs1;  // row stride 64
    int start = (v == 0) ? 0 : rowptr[v - 1];
    int end = rowptr[v];
    float2 self = H[(size_t)v * 64 + c2];
    float ax = 2.f * self.x, ay = 2.f * self.y;
    int j = start;
    for (; j + 4 <= end; j += 4) {
        int s0 = col[j], s1 = col[j + 1], s2 = col[j + 2], s3 = col[j + 3];
        float2 v0 = H[(size_t)s0 * 64 + c2];
        float2 v1 = H[(size_t)s1 * 64 + c2];
        float2 v2 = H[(size_t)s2 * 64 + c2];
        float2 v3 = H[(size_t)s3 * 64 + c2];
        ax += v0.x + v1.x + v2.x + v3.x;
        ay += v0.y + v1.y + v2.y + v3.y;
    }
    for (; j < end; ++j) {
        float2 u = H[(size_t)col[j] * 64 + c2];
        ax += u.x; ay += u.y;
    }
    float di = dinv[v];
    int c = c2 * 2;
    float2 r;
    r.x = fmaxf(di * ax + b1[c], 0.f);
    r.y = fmaxf(di * ay + b1[c + 1], 0.f);
    ((float2*)h1)[(size_t)v * 64 + c2] = r;
}

// ---------------- agg2: CSR gather + bias + log_softmax (one wave per row), unroll 4 ----------------
__global__ void agg2_csr(const int* __restrict__ rowptr, const int* __restrict__ col,
                         const float* __restrict__ hs2, const float* __restrict__ dinv,
                         const float* __restrict__ b2, float* __restrict__ out) {
    int t = threadIdx.x;
    int v = blockIdx.x * 4 + (t >> 6);
    int c = t & 63;
    int start = (v == 0) ? 0 : rowptr[v - 1];
    int end = rowptr[v];
    float acc = 2.f * hs2[(size_t)v * CD + c];
    int j = start;
    for (; j + 4 <= end; j += 4) {
        int s0 = col[j], s1 = col[j + 1], s2 = col[j + 2], s3 = col[j + 3];
        acc += hs2[(size_t)s0 * CD + c] + hs2[(size_t)s1 * CD + c] +
               hs2[(size_t)s2 * CD + c] + hs2[(size_t)s3 * CD + c];
    }
    for (; j < end; ++j) acc += hs2[(size_t)col[j] * CD + c];
    float o = dinv[v] * acc + b2[c];
    float m = o;
#pragma unroll
    for (int off = 32; off >= 1; off >>= 1) m = fmaxf(m, __shfl_xor(m, off, 64));
    float ex = __expf(o - m);
    float s = ex;
#pragma unroll
    for (int off = 32; off >= 1; off >>= 1) s += __shfl_xor(s, off, 64);
    out[(size_t)v * CD + c] = o - m - __logf(s);
}

extern "C" void kernel_launch(void* const* d_in, const int* in_sizes, int n_in,
                              void* d_out, int out_size, void* d_ws, size_t ws_size,
                              hipStream_t stream) {
    const float* x  = (const float*)d_in[0];
    const int*   ei = (const int*)d_in[1];   // [2, E] int32
    const float* W1 = (const float*)d_in[2];
    const float* b1 = (const float*)d_in[3];
    const float* W2 = (const float*)d_in[4];
    const float* b2 = (const float*)d_in[5];
    float* out = (float*)d_out;

    const int* src = ei;
    const int* dst = ei + NE;

    float* ws = (float*)d_ws;
    float* dinv   = ws;                        // NN floats
    int*   rowptr = (int*)(ws + 65536);        // NN ints
    int*   col    = (int*)(ws + 131072);       // NE ints
    int*   sums   = (int*)(ws + 931072);       // 64 ints
    float* hs1    = ws + 933888;               // NN*HD
    float* h1     = ws + 7333888;              // NN*HD
    float* hs2    = hs1;                       // reuse (hs1 dead after agg1)

    // ---- CSR build ----
    hipMemsetAsync(rowptr, 0, (size_t)NN * sizeof(int), stream);
    count_deg<<<(NE + 255) / 256, 256, 0, stream>>>(dst, rowptr);
    scan_a<<<NCHUNK, 1024, 0, stream>>>(rowptr, sums, dinv);
    scan_b<<<1, 64, 0, stream>>>(sums);
    scan_c<<<(NN + 255) / 256, 256, 0, stream>>>(rowptr, sums);
    fill_csr<<<(NE + 255) / 256, 256, 0, stream>>>(src, dst, rowptr, col);

    // ---- layer 1 ----
    gemm1<<<(NN + 63) / 64, 256, 0, stream>>>(x, W1, dinv, hs1);
    agg1_csr<<<NN / 4, 256, 0, stream>>>(rowptr, col, hs1, dinv, b1, h1);

    // ---- layer 2 ----
    gemm2<<<(NN + 63) / 64, 256, 0, stream>>>(h1, W2, dinv, hs2);
    agg2_csr<<<NN / 4, 256, 0, stream>>>(rowptr, col, hs2, dinv, b2, out);
}

// Round 11
// 236.528 us; speedup vs baseline: 1.3949x; 1.0843x over previous
//
#include <hip/hip_runtime.h>
#include <hip/hip_fp16.h>

#define NN 50000
#define NE 800000
#define DIN 128
#define HD 128
#define CD 64
#define NCHUNK ((NN + 1023) / 1024)  // 49
#define XSTR 132                     // padded x-tile row stride (floats)

// ---------------- CSR build ----------------
__global__ void count_deg(const int* __restrict__ dst, int* __restrict__ cnt) {
    int e = blockIdx.x * blockDim.x + threadIdx.x;
    if (e < NE) atomicAdd(&cnt[dst[e]], 1);
}

// chunk-local exclusive scan + chunk totals; also emits dinv = rsqrt(cnt+2)
__global__ void __launch_bounds__(1024) scan_a(int* __restrict__ cnt, int* __restrict__ sums,
                                               float* __restrict__ dinv) {
    __shared__ int wsum[16];
    int t = threadIdx.x;
    int i = blockIdx.x * 1024 + t;
    int v = (i < NN) ? cnt[i] : 0;
    if (i < NN) dinv[i] = rsqrtf((float)(v + 2));  // +2 self loops
    int x = v;
#pragma unroll
    for (int off = 1; off < 64; off <<= 1) {
        int y = __shfl_up(x, off, 64);
        if ((t & 63) >= off) x += y;
    }
    int wid = t >> 6;
    if ((t & 63) == 63) wsum[wid] = x;
    __syncthreads();
    if (t < 16) {
        int s = wsum[t];
#pragma unroll
        for (int off = 1; off < 16; off <<= 1) {
            int y = __shfl_up(s, off, 16);
            if (t >= off) s += y;
        }
        wsum[t] = s;
    }
    __syncthreads();
    int base = (wid > 0) ? wsum[wid - 1] : 0;
    int incl = base + x;
    if (i < NN) cnt[i] = incl - v;  // exclusive within chunk
    if (t == 1023) sums[blockIdx.x] = incl;
}

__global__ void scan_b(int* __restrict__ sums) {
    int t = threadIdx.x;
    int v = (t < NCHUNK) ? sums[t] : 0;
    int x = v;
#pragma unroll
    for (int off = 1; off < 64; off <<= 1) {
        int y = __shfl_up(x, off, 64);
        if (t >= off) x += y;
    }
    if (t < NCHUNK) sums[t] = x - v;  // exclusive chunk bases
}

__global__ void scan_c(int* __restrict__ cnt, const int* __restrict__ sums) {
    int i = blockIdx.x * blockDim.x + threadIdx.x;
    if (i < NN) cnt[i] += sums[i >> 10];
}

// after fill: rowptr[v] == end offset of row v (start is rowptr[v-1])
__global__ void fill_csr(const int* __restrict__ src, const int* __restrict__ dst,
                         int* __restrict__ rowptr, int* __restrict__ col) {
    int e = blockIdx.x * blockDim.x + threadIdx.x;
    if (e < NE) {
        int d = dst[e];
        int pos = atomicAdd(&rowptr[d], 1);
        col[pos] = src[e];
    }
}

// ---------------- GEMM1: hs1(fp16) = dinv * (x @ W1) ----------------
// 256t / 4 waves / 64 rows per block. W1 (64KB) + padded x-tile (33.8KB) in LDS.
// Wave = 16 col-lanes x 4 row-groups; acc[4 rows][8 cols] (cols {4cl, 64+4cl}).
__global__ void __launch_bounds__(256, 1) gemm1(const float* __restrict__ x, const float* __restrict__ W1,
                                                const float* __restrict__ dinv, __half* __restrict__ hs1) {
    __shared__ float w[DIN * HD];     // [k][c] 64 KB
    __shared__ float xs[64 * XSTR];   // [r][k] padded, 33.8 KB
    int t = threadIdx.x;
    int row0 = blockIdx.x * 64;
    {
        const float4* Wg = (const float4*)W1;
        float4* wv = (float4*)w;
#pragma unroll
        for (int i = 0; i < 16; ++i) wv[t + 256 * i] = Wg[t + 256 * i];
    }
    {
#pragma unroll
        for (int i = 0; i < 8; ++i) {
            int m = t + 256 * i;
            int r = m >> 5, kq = m & 31;
            int gr = row0 + r; if (gr > NN - 1) gr = NN - 1;
            float4 v = ((const float4*)x)[(size_t)gr * 32 + kq];
            *(float4*)&xs[r * XSTR + 4 * kq] = v;
        }
    }
    __syncthreads();

    int lane = t & 63, wv_id = t >> 6;
    int cl = lane & 15, g = lane >> 4;
    int wrow = wv_id * 16 + g * 4;
    int ca = 4 * cl;
    int cb = 64 + 4 * cl;

    float4 acc[4][2];
#pragma unroll
    for (int r = 0; r < 4; ++r) { acc[r][0] = make_float4(0,0,0,0); acc[r][1] = make_float4(0,0,0,0); }

#pragma unroll 2
    for (int kq = 0; kq < 32; ++kq) {
        float4 xv[4];
#pragma unroll
        for (int rr = 0; rr < 4; ++rr)
            xv[rr] = *(const float4*)&xs[(wrow + rr) * XSTR + 4 * kq];
#pragma unroll
        for (int j = 0; j < 4; ++j) {
            float4 wa = *(const float4*)&w[(4 * kq + j) * HD + ca];
            float4 wb = *(const float4*)&w[(4 * kq + j) * HD + cb];
#pragma unroll
            for (int rr = 0; rr < 4; ++rr) {
                float xj = (j == 0) ? xv[rr].x : (j == 1) ? xv[rr].y : (j == 2) ? xv[rr].z : xv[rr].w;
                acc[rr][0].x += xj * wa.x; acc[rr][0].y += xj * wa.y;
                acc[rr][0].z += xj * wa.z; acc[rr][0].w += xj * wa.w;
                acc[rr][1].x += xj * wb.x; acc[rr][1].y += xj * wb.y;
                acc[rr][1].z += xj * wb.z; acc[rr][1].w += xj * wb.w;
            }
        }
    }
#pragma unroll
    for (int rr = 0; rr < 4; ++rr) {
        int row = row0 + wrow + rr;
        if (row < NN) {
            float di = dinv[row];
            float4 oa = acc[rr][0], ob = acc[rr][1];
            union { __half2 h[2]; uint2 u; } pa, pb;
            pa.h[0] = __floats2half2_rn(oa.x * di, oa.y * di);
            pa.h[1] = __floats2half2_rn(oa.z * di, oa.w * di);
            pb.h[0] = __floats2half2_rn(ob.x * di, ob.y * di);
            pb.h[1] = __floats2half2_rn(ob.z * di, ob.w * di);
            *(uint2*)&hs1[(size_t)row * HD + ca] = pa.u;
            *(uint2*)&hs1[(size_t)row * HD + cb] = pb.u;
        }
    }
}

// ---------------- GEMM2: hs2(fp16) = dinv * (h1 @ W2) ----------------
__global__ void __launch_bounds__(256, 2) gemm2(const float* __restrict__ h1, const float* __restrict__ W2,
                                                const float* __restrict__ dinv, __half* __restrict__ hs2) {
    __shared__ float w[DIN * CD];     // 32 KB
    __shared__ float xs[64 * XSTR];   // 33.8 KB
    int t = threadIdx.x;
    int row0 = blockIdx.x * 64;
    {
        const float4* Wg = (const float4*)W2;
        float4* wv = (float4*)w;
#pragma unroll
        for (int i = 0; i < 8; ++i) wv[t + 256 * i] = Wg[t + 256 * i];
    }
    {
#pragma unroll
        for (int i = 0; i < 8; ++i) {
            int m = t + 256 * i;
            int r = m >> 5, kq = m & 31;
            int gr = row0 + r; if (gr > NN - 1) gr = NN - 1;
            float4 v = ((const float4*)h1)[(size_t)gr * 32 + kq];
            *(float4*)&xs[r * XSTR + 4 * kq] = v;
        }
    }
    __syncthreads();

    int lane = t & 63, wv_id = t >> 6;
    int cl = lane & 15, g = lane >> 4;
    int wrow = wv_id * 16 + g * 4;
    int ca = 4 * cl;

    float4 acc[4];
#pragma unroll
    for (int r = 0; r < 4; ++r) acc[r] = make_float4(0,0,0,0);

#pragma unroll 2
    for (int kq = 0; kq < 32; ++kq) {
        float4 xv[4];
#pragma unroll
        for (int rr = 0; rr < 4; ++rr)
            xv[rr] = *(const float4*)&xs[(wrow + rr) * XSTR + 4 * kq];
#pragma unroll
        for (int j = 0; j < 4; ++j) {
            float4 wa = *(const float4*)&w[(4 * kq + j) * CD + ca];
#pragma unroll
            for (int rr = 0; rr < 4; ++rr) {
                float xj = (j == 0) ? xv[rr].x : (j == 1) ? xv[rr].y : (j == 2) ? xv[rr].z : xv[rr].w;
                acc[rr].x += xj * wa.x; acc[rr].y += xj * wa.y;
                acc[rr].z += xj * wa.z; acc[rr].w += xj * wa.w;
            }
        }
    }
#pragma unroll
    for (int rr = 0; rr < 4; ++rr) {
        int row = row0 + wrow + rr;
        if (row < NN) {
            float di = dinv[row];
            float4 o = acc[rr];
            union { __half2 h[2]; uint2 u; } p;
            p.h[0] = __floats2half2_rn(o.x * di, o.y * di);
            p.h[1] = __floats2half2_rn(o.z * di, o.w * di);
            *(uint2*)&hs2[(size_t)row * CD + ca] = p.u;
        }
    }
}

// ---------------- agg1: CSR gather of fp16 rows (half2/lane), unroll 8, fp32 accum ----------------
__global__ void agg1_csr(const int* __restrict__ rowptr, const int* __restrict__ col,
                         const __half* __restrict__ hs1, const float* __restrict__ dinv,
                         const float* __restrict__ b1, float* __restrict__ h1) {
    int t = threadIdx.x;
    int v = blockIdx.x * 4 + (t >> 6);
    int c2 = t & 63;  // half2 col-pair index
    const __half2* H = (const __half2*)hs1;  // row stride 64
    int start = (v == 0) ? 0 : rowptr[v - 1];
    int end = rowptr[v];
    float2 sf = __half22float2(H[(size_t)v * 64 + c2]);
    float ax = 2.f * sf.x, ay = 2.f * sf.y;
    int j = start;
    for (; j + 8 <= end; j += 8) {
        int s0 = col[j], s1 = col[j + 1], s2 = col[j + 2], s3 = col[j + 3];
        int s4 = col[j + 4], s5 = col[j + 5], s6 = col[j + 6], s7 = col[j + 7];
        float2 v0 = __half22float2(H[(size_t)s0 * 64 + c2]);
        float2 v1 = __half22float2(H[(size_t)s1 * 64 + c2]);
        float2 v2 = __half22float2(H[(size_t)s2 * 64 + c2]);
        float2 v3 = __half22float2(H[(size_t)s3 * 64 + c2]);
        float2 v4 = __half22float2(H[(size_t)s4 * 64 + c2]);
        float2 v5 = __half22float2(H[(size_t)s5 * 64 + c2]);
        float2 v6 = __half22float2(H[(size_t)s6 * 64 + c2]);
        float2 v7 = __half22float2(H[(size_t)s7 * 64 + c2]);
        ax += ((v0.x + v1.x) + (v2.x + v3.x)) + ((v4.x + v5.x) + (v6.x + v7.x));
        ay += ((v0.y + v1.y) + (v2.y + v3.y)) + ((v4.y + v5.y) + (v6.y + v7.y));
    }
    for (; j < end; ++j) {
        float2 u = __half22float2(H[(size_t)col[j] * 64 + c2]);
        ax += u.x; ay += u.y;
    }
    float di = dinv[v];
    int c = c2 * 2;
    float2 r;
    r.x = fmaxf(di * ax + b1[c], 0.f);
    r.y = fmaxf(di * ay + b1[c + 1], 0.f);
    ((float2*)h1)[(size_t)v * 64 + c2] = r;
}

// ---------------- agg2: CSR gather of fp16 rows + bias + log_softmax, unroll 8 ----------------
__global__ void agg2_csr(const int* __restrict__ rowptr, const int* __restrict__ col,
                         const __half* __restrict__ hs2, const float* __restrict__ dinv,
                         const float* __restrict__ b2, float* __restrict__ out) {
    int t = threadIdx.x;
    int v = blockIdx.x * 4 + (t >> 6);
    int c = t & 63;
    int start = (v == 0) ? 0 : rowptr[v - 1];
    int end = rowptr[v];
    float acc = 2.f * __half2float(hs2[(size_t)v * CD + c]);
    int j = start;
    for (; j + 8 <= end; j += 8) {
        int s0 = col[j], s1 = col[j + 1], s2 = col[j + 2], s3 = col[j + 3];
        int s4 = col[j + 4], s5 = col[j + 5], s6 = col[j + 6], s7 = col[j + 7];
        float a0 = __half2float(hs2[(size_t)s0 * CD + c]), a1 = __half2float(hs2[(size_t)s1 * CD + c]);
        float a2 = __half2float(hs2[(size_t)s2 * CD + c]), a3 = __half2float(hs2[(size_t)s3 * CD + c]);
        float a4 = __half2float(hs2[(size_t)s4 * CD + c]), a5 = __half2float(hs2[(size_t)s5 * CD + c]);
        float a6 = __half2float(hs2[(size_t)s6 * CD + c]), a7 = __half2float(hs2[(size_t)s7 * CD + c]);
        acc += ((a0 + a1) + (a2 + a3)) + ((a4 + a5) + (a6 + a7));
    }
    for (; j < end; ++j) acc += __half2float(hs2[(size_t)col[j] * CD + c]);
    float o = dinv[v] * acc + b2[c];
    float m = o;
#pragma unroll
    for (int off = 32; off >= 1; off >>= 1) m = fmaxf(m, __shfl_xor(m, off, 64));
    float ex = __expf(o - m);
    float s = ex;
#pragma unroll
    for (int off = 32; off >= 1; off >>= 1) s += __shfl_xor(s, off, 64);
    out[(size_t)v * CD + c] = o - m - __logf(s);
}

extern "C" void kernel_launch(void* const* d_in, const int* in_sizes, int n_in,
                              void* d_out, int out_size, void* d_ws, size_t ws_size,
                              hipStream_t stream) {
    const float* x  = (const float*)d_in[0];
    const int*   ei = (const int*)d_in[1];   // [2, E] int32
    const float* W1 = (const float*)d_in[2];
    const float* b1 = (const float*)d_in[3];
    const float* W2 = (const float*)d_in[4];
    const float* b2 = (const float*)d_in[5];
    float* out = (float*)d_out;

    const int* src = ei;
    const int* dst = ei + NE;

    float* ws = (float*)d_ws;
    float*  dinv   = ws;                        // NN floats
    int*    rowptr = (int*)(ws + 65536);        // NN ints
    int*    col    = (int*)(ws + 131072);       // NE ints
    int*    sums   = (int*)(ws + 931072);       // 64 ints
    __half* hs1    = (__half*)(ws + 933888);    // NN*HD halves (fits in old region)
    float*  h1     = ws + 7333888;              // NN*HD floats
    __half* hs2    = hs1;                       // reuse (hs1 dead after agg1)

    // ---- CSR build ----
    hipMemsetAsync(rowptr, 0, (size_t)NN * sizeof(int), stream);
    count_deg<<<(NE + 255) / 256, 256, 0, stream>>>(dst, rowptr);
    scan_a<<<NCHUNK, 1024, 0, stream>>>(rowptr, sums, dinv);
    scan_b<<<1, 64, 0, stream>>>(sums);
    scan_c<<<(NN + 255) / 256, 256, 0, stream>>>(rowptr, sums);
    fill_csr<<<(NE + 255) / 256, 256, 0, stream>>>(src, dst, rowptr, col);

    // ---- layer 1 ----
    gemm1<<<(NN + 63) / 64, 256, 0, stream>>>(x, W1, dinv, hs1);
    agg1_csr<<<NN / 4, 256, 0, stream>>>(rowptr, col, hs1, dinv, b1, h1);

    // ---- layer 2 ----
    gemm2<<<(NN + 63) / 64, 256, 0, stream>>>(h1, W2, dinv, hs2);
    agg2_csr<<<NN / 4, 256, 0, stream>>>(rowptr, col, hs2, dinv, b2, out);
}

// Round 12
// 178.121 us; speedup vs baseline: 1.8523x; 1.3279x over previous
//
#include <hip/hip_runtime.h>
#include <hip/hip_fp16.h>

#define NN 50000
#define NE 800000
#define DIN 128
#define HD 128
#define CD 64
#define XSTR 132      // padded x-tile row stride (floats)
#define NB 196        // dst buckets of 256 nodes (50000/256 -> 196)
#define BP 128        // partition blocks
#define EPB 6250      // edges per partition block (128*6250 == 800000)
#define NP (NB * BP)  // 25088
#define NPCHUNK ((NP + 1023) / 1024)  // 25

// ---------------- P1: per-(bucket,block) histogram, LDS only ----------------
__global__ void __launch_bounds__(256) p1_hist(const int* __restrict__ dst, int* __restrict__ cntMatT) {
    __shared__ int hist[NB];
    int t = threadIdx.x, blk = blockIdx.x;
    if (t < NB) hist[t] = 0;
    __syncthreads();
    int base = blk * EPB;
    for (int i = base + t; i < base + EPB; i += 256)
        atomicAdd(&hist[dst[i] >> 8], 1);
    __syncthreads();
    if (t < NB) cntMatT[t * BP + blk] = hist[t];  // bucket-major
}

// ---------------- pscan: hierarchical exclusive scan of cntMatT (25088) ----------------
__global__ void __launch_bounds__(1024) pscan_a(int* __restrict__ c, int* __restrict__ sums) {
    __shared__ int wsum[16];
    int t = threadIdx.x;
    int i = blockIdx.x * 1024 + t;
    int v = (i < NP) ? c[i] : 0;
    int x = v;
#pragma unroll
    for (int off = 1; off < 64; off <<= 1) {
        int y = __shfl_up(x, off, 64);
        if ((t & 63) >= off) x += y;
    }
    int wid = t >> 6;
    if ((t & 63) == 63) wsum[wid] = x;
    __syncthreads();
    if (t < 16) {
        int s = wsum[t];
#pragma unroll
        for (int off = 1; off < 16; off <<= 1) {
            int y = __shfl_up(s, off, 16);
            if (t >= off) s += y;
        }
        wsum[t] = s;
    }
    __syncthreads();
    int basew = (wid > 0) ? wsum[wid - 1] : 0;
    int incl = basew + x;
    if (i < NP) c[i] = incl - v;  // exclusive within chunk
    if (t == 1023) sums[blockIdx.x] = incl;
}

__global__ void pscan_b(int* __restrict__ sums) {
    int t = threadIdx.x;
    int v = (t < NPCHUNK) ? sums[t] : 0;
    int x = v;
#pragma unroll
    for (int off = 1; off < 64; off <<= 1) {
        int y = __shfl_up(x, off, 64);
        if (t >= off) x += y;
    }
    if (t < NPCHUNK) sums[t] = x - v;
}

__global__ void pscan_c(int* __restrict__ c, const int* __restrict__ sums) {
    int i = blockIdx.x * blockDim.x + threadIdx.x;
    if (i < NP) c[i] += sums[i >> 10];
}

// ---------------- P3: partition edges into bucket-major segments ----------------
// part[pos] = src | (dst&255)<<16  (src < 2^16, d_local < 2^8)
__global__ void __launch_bounds__(256) p3_scatter(const int* __restrict__ src, const int* __restrict__ dst,
                                                  const int* __restrict__ cntMatT, unsigned int* __restrict__ part) {
    __shared__ int cur[NB];
    int t = threadIdx.x, blk = blockIdx.x;
    if (t < NB) cur[t] = cntMatT[t * BP + blk];
    __syncthreads();
    int base = blk * EPB;
    for (int i = base + t; i < base + EPB; i += 256) {
        int d = dst[i];
        int b = d >> 8;
        int pos = atomicAdd(&cur[b], 1);
        part[pos] = (unsigned int)src[i] | ((unsigned int)(d & 255) << 16);
    }
}

// ---------------- fill2: per-bucket local CSR build (also emits rowptr starts + dinv) ----------------
__global__ void __launch_bounds__(256) fill2(const int* __restrict__ cntMatT, const unsigned int* __restrict__ part,
                                             int* __restrict__ rowptr, float* __restrict__ dinv,
                                             int* __restrict__ col) {
    __shared__ int cnt[256];
    __shared__ int wsum[4];
    int t = threadIdx.x, b = blockIdx.x;
    int base = cntMatT[b * BP];                       // bucket start offset
    int endb = (b < NB - 1) ? cntMatT[(b + 1) * BP] : NE;
    cnt[t] = 0;
    __syncthreads();
    for (int i = base + t; i < endb; i += 256)
        atomicAdd(&cnt[part[i] >> 16], 1);
    __syncthreads();
    int v = cnt[t];
    int x = v;
#pragma unroll
    for (int off = 1; off < 64; off <<= 1) {
        int y = __shfl_up(x, off, 64);
        if ((t & 63) >= off) x += y;
    }
    int wid = t >> 6;
    if ((t & 63) == 63) wsum[wid] = x;
    __syncthreads();
    if (t < 4) {
        int s = wsum[t];
#pragma unroll
        for (int off = 1; off < 4; off <<= 1) {
            int y = __shfl_up(s, off, 4);
            if (t >= off) s += y;
        }
        wsum[t] = s;
    }
    __syncthreads();
    int bw = (wid > 0) ? wsum[wid - 1] : 0;
    int start = base + bw + x - v;                    // exclusive
    int node = b * 256 + t;
    if (node < NN) {
        rowptr[node] = start;
        dinv[node] = rsqrtf((float)(v + 2));          // +2 self loops
    }
    __syncthreads();
    cnt[t] = start;                                   // cursor
    __syncthreads();
    for (int i = base + t; i < endb; i += 256) {
        unsigned int u = part[i];
        int pos = atomicAdd(&cnt[u >> 16], 1);
        col[pos] = (int)(u & 0xFFFFu);
    }
    if (b == NB - 1 && t == 0) rowptr[NN] = NE;
}

// ---------------- GEMM1: hs1(fp16) = dinv * (x @ W1) ----------------
__global__ void __launch_bounds__(256, 1) gemm1(const float* __restrict__ x, const float* __restrict__ W1,
                                                const float* __restrict__ dinv, __half* __restrict__ hs1) {
    __shared__ float w[DIN * HD];     // 64 KB
    __shared__ float xs[64 * XSTR];   // 33.8 KB
    int t = threadIdx.x;
    int row0 = blockIdx.x * 64;
    {
        const float4* Wg = (const float4*)W1;
        float4* wv = (float4*)w;
#pragma unroll
        for (int i = 0; i < 16; ++i) wv[t + 256 * i] = Wg[t + 256 * i];
    }
    {
#pragma unroll
        for (int i = 0; i < 8; ++i) {
            int m = t + 256 * i;
            int r = m >> 5, kq = m & 31;
            int gr = row0 + r; if (gr > NN - 1) gr = NN - 1;
            float4 v = ((const float4*)x)[(size_t)gr * 32 + kq];
            *(float4*)&xs[r * XSTR + 4 * kq] = v;
        }
    }
    __syncthreads();

    int lane = t & 63, wv_id = t >> 6;
    int cl = lane & 15, g = lane >> 4;
    int wrow = wv_id * 16 + g * 4;
    int ca = 4 * cl;
    int cb = 64 + 4 * cl;

    float4 acc[4][2];
#pragma unroll
    for (int r = 0; r < 4; ++r) { acc[r][0] = make_float4(0,0,0,0); acc[r][1] = make_float4(0,0,0,0); }

#pragma unroll 2
    for (int kq = 0; kq < 32; ++kq) {
        float4 xv[4];
#pragma unroll
        for (int rr = 0; rr < 4; ++rr)
            xv[rr] = *(const float4*)&xs[(wrow + rr) * XSTR + 4 * kq];
#pragma unroll
        for (int j = 0; j < 4; ++j) {
            float4 wa = *(const float4*)&w[(4 * kq + j) * HD + ca];
            float4 wb = *(const float4*)&w[(4 * kq + j) * HD + cb];
#pragma unroll
            for (int rr = 0; rr < 4; ++rr) {
                float xj = (j == 0) ? xv[rr].x : (j == 1) ? xv[rr].y : (j == 2) ? xv[rr].z : xv[rr].w;
                acc[rr][0].x += xj * wa.x; acc[rr][0].y += xj * wa.y;
                acc[rr][0].z += xj * wa.z; acc[rr][0].w += xj * wa.w;
                acc[rr][1].x += xj * wb.x; acc[rr][1].y += xj * wb.y;
                acc[rr][1].z += xj * wb.z; acc[rr][1].w += xj * wb.w;
            }
        }
    }
#pragma unroll
    for (int rr = 0; rr < 4; ++rr) {
        int row = row0 + wrow + rr;
        if (row < NN) {
            float di = dinv[row];
            float4 oa = acc[rr][0], ob = acc[rr][1];
            union { __half2 h[2]; uint2 u; } pa, pb;
            pa.h[0] = __floats2half2_rn(oa.x * di, oa.y * di);
            pa.h[1] = __floats2half2_rn(oa.z * di, oa.w * di);
            pb.h[0] = __floats2half2_rn(ob.x * di, ob.y * di);
            pb.h[1] = __floats2half2_rn(ob.z * di, ob.w * di);
            *(uint2*)&hs1[(size_t)row * HD + ca] = pa.u;
            *(uint2*)&hs1[(size_t)row * HD + cb] = pb.u;
        }
    }
}

// ---------------- GEMM2: hs2(fp16) = dinv * (h1 @ W2) ----------------
__global__ void __launch_bounds__(256, 2) gemm2(const float* __restrict__ h1, const float* __restrict__ W2,
                                                const float* __restrict__ dinv, __half* __restrict__ hs2) {
    __shared__ float w[DIN * CD];     // 32 KB
    __shared__ float xs[64 * XSTR];   // 33.8 KB
    int t = threadIdx.x;
    int row0 = blockIdx.x * 64;
    {
        const float4* Wg = (const float4*)W2;
        float4* wv = (float4*)w;
#pragma unroll
        for (int i = 0; i < 8; ++i) wv[t + 256 * i] = Wg[t + 256 * i];
    }
    {
#pragma unroll
        for (int i = 0; i < 8; ++i) {
            int m = t + 256 * i;
            int r = m >> 5, kq = m & 31;
            int gr = row0 + r; if (gr > NN - 1) gr = NN - 1;
            float4 v = ((const float4*)h1)[(size_t)gr * 32 + kq];
            *(float4*)&xs[r * XSTR + 4 * kq] = v;
        }
    }
    __syncthreads();

    int lane = t & 63, wv_id = t >> 6;
    int cl = lane & 15, g = lane >> 4;
    int wrow = wv_id * 16 + g * 4;
    int ca = 4 * cl;

    float4 acc[4];
#pragma unroll
    for (int r = 0; r < 4; ++r) acc[r] = make_float4(0,0,0,0);

#pragma unroll 2
    for (int kq = 0; kq < 32; ++kq) {
        float4 xv[4];
#pragma unroll
        for (int rr = 0; rr < 4; ++rr)
            xv[rr] = *(const float4*)&xs[(wrow + rr) * XSTR + 4 * kq];
#pragma unroll
        for (int j = 0; j < 4; ++j) {
            float4 wa = *(const float4*)&w[(4 * kq + j) * CD + ca];
#pragma unroll
            for (int rr = 0; rr < 4; ++rr) {
                float xj = (j == 0) ? xv[rr].x : (j == 1) ? xv[rr].y : (j == 2) ? xv[rr].z : xv[rr].w;
                acc[rr].x += xj * wa.x; acc[rr].y += xj * wa.y;
                acc[rr].z += xj * wa.z; acc[rr].w += xj * wa.w;
            }
        }
    }
#pragma unroll
    for (int rr = 0; rr < 4; ++rr) {
        int row = row0 + wrow + rr;
        if (row < NN) {
            float di = dinv[row];
            float4 o = acc[rr];
            union { __half2 h[2]; uint2 u; } p;
            p.h[0] = __floats2half2_rn(o.x * di, o.y * di);
            p.h[1] = __floats2half2_rn(o.z * di, o.w * di);
            *(uint2*)&hs2[(size_t)row * CD + ca] = p.u;
        }
    }
}

// ---------------- agg1: CSR gather of fp16 rows (half2/lane), unroll 8, fp32 accum ----------------
__global__ void agg1_csr(const int* __restrict__ rowptr, const int* __restrict__ col,
                         const __half* __restrict__ hs1, const float* __restrict__ dinv,
                         const float* __restrict__ b1, float* __restrict__ h1) {
    int t = threadIdx.x;
    int v = blockIdx.x * 4 + (t >> 6);
    int c2 = t & 63;
    const __half2* H = (const __half2*)hs1;  // row stride 64
    int start = rowptr[v];
    int end = rowptr[v + 1];
    float2 sf = __half22float2(H[(size_t)v * 64 + c2]);
    float ax = 2.f * sf.x, ay = 2.f * sf.y;
    int j = start;
    for (; j + 8 <= end; j += 8) {
        int s0 = col[j], s1 = col[j + 1], s2 = col[j + 2], s3 = col[j + 3];
        int s4 = col[j + 4], s5 = col[j + 5], s6 = col[j + 6], s7 = col[j + 7];
        float2 v0 = __half22float2(H[(size_t)s0 * 64 + c2]);
        float2 v1 = __half22float2(H[(size_t)s1 * 64 + c2]);
        float2 v2 = __half22float2(H[(size_t)s2 * 64 + c2]);
        float2 v3 = __half22float2(H[(size_t)s3 * 64 + c2]);
        float2 v4 = __half22float2(H[(size_t)s4 * 64 + c2]);
        float2 v5 = __half22float2(H[(size_t)s5 * 64 + c2]);
        float2 v6 = __half22float2(H[(size_t)s6 * 64 + c2]);
        float2 v7 = __half22float2(H[(size_t)s7 * 64 + c2]);
        ax += ((v0.x + v1.x) + (v2.x + v3.x)) + ((v4.x + v5.x) + (v6.x + v7.x));
        ay += ((v0.y + v1.y) + (v2.y + v3.y)) + ((v4.y + v5.y) + (v6.y + v7.y));
    }
    for (; j < end; ++j) {
        float2 u = __half22float2(H[(size_t)col[j] * 64 + c2]);
        ax += u.x; ay += u.y;
    }
    float di = dinv[v];
    int c = c2 * 2;
    float2 r;
    r.x = fmaxf(di * ax + b1[c], 0.f);
    r.y = fmaxf(di * ay + b1[c + 1], 0.f);
    ((float2*)h1)[(size_t)v * 64 + c2] = r;
}

// ---------------- agg2: CSR gather of fp16 rows + bias + log_softmax, unroll 8 ----------------
__global__ void agg2_csr(const int* __restrict__ rowptr, const int* __restrict__ col,
                         const __half* __restrict__ hs2, const float* __restrict__ dinv,
                         const float* __restrict__ b2, float* __restrict__ out) {
    int t = threadIdx.x;
    int v = blockIdx.x * 4 + (t >> 6);
    int c = t & 63;
    int start = rowptr[v];
    int end = rowptr[v + 1];
    float acc = 2.f * __half2float(hs2[(size_t)v * CD + c]);
    int j = start;
    for (; j + 8 <= end; j += 8) {
        int s0 = col[j], s1 = col[j + 1], s2 = col[j + 2], s3 = col[j + 3];
        int s4 = col[j + 4], s5 = col[j + 5], s6 = col[j + 6], s7 = col[j + 7];
        float a0 = __half2float(hs2[(size_t)s0 * CD + c]), a1 = __half2float(hs2[(size_t)s1 * CD + c]);
        float a2 = __half2float(hs2[(size_t)s2 * CD + c]), a3 = __half2float(hs2[(size_t)s3 * CD + c]);
        float a4 = __half2float(hs2[(size_t)s4 * CD + c]), a5 = __half2float(hs2[(size_t)s5 * CD + c]);
        float a6 = __half2float(hs2[(size_t)s6 * CD + c]), a7 = __half2float(hs2[(size_t)s7 * CD + c]);
        acc += ((a0 + a1) + (a2 + a3)) + ((a4 + a5) + (a6 + a7));
    }
    for (; j < end; ++j) acc += __half2float(hs2[(size_t)col[j] * CD + c]);
    float o = dinv[v] * acc + b2[c];
    float m = o;
#pragma unroll
    for (int off = 32; off >= 1; off >>= 1) m = fmaxf(m, __shfl_xor(m, off, 64));
    float ex = __expf(o - m);
    float s = ex;
#pragma unroll
    for (int off = 32; off >= 1; off >>= 1) s += __shfl_xor(s, off, 64);
    out[(size_t)v * CD + c] = o - m - __logf(s);
}

extern "C" void kernel_launch(void* const* d_in, const int* in_sizes, int n_in,
                              void* d_out, int out_size, void* d_ws, size_t ws_size,
                              hipStream_t stream) {
    const float* x  = (const float*)d_in[0];
    const int*   ei = (const int*)d_in[1];   // [2, E] int32
    const float* W1 = (const float*)d_in[2];
    const float* b1 = (const float*)d_in[3];
    const float* W2 = (const float*)d_in[4];
    const float* b2 = (const float*)d_in[5];
    float* out = (float*)d_out;

    const int* src = ei;
    const int* dst = ei + NE;

    float* ws = (float*)d_ws;
    float*        dinv    = ws;                              // NN floats
    int*          rowptr  = (int*)(ws + 65536);              // NN+1 ints
    int*          col     = (int*)(ws + 131072);             // NE ints -> 931072
    int*          cntMatT = (int*)(ws + 931136);             // NP ints -> 956224
    int*          psums   = (int*)(ws + 956224);             // 25 ints
    unsigned int* part    = (unsigned int*)(ws + 960000);    // NE u32 -> 1760000
    __half*       hs1     = (__half*)(ws + 1760000);         // NN*HD halves -> 4960000
    float*        h1      = ws + 4960000;                    // NN*HD floats -> 11360000
    __half*       hs2     = hs1;                             // reuse

    // ---- CSR build: partition -> local fill (no global atomics anywhere) ----
    p1_hist<<<BP, 256, 0, stream>>>(dst, cntMatT);
    pscan_a<<<NPCHUNK, 1024, 0, stream>>>(cntMatT, psums);
    pscan_b<<<1, 64, 0, stream>>>(psums);
    pscan_c<<<(NP + 255) / 256, 256, 0, stream>>>(cntMatT, psums);
    p3_scatter<<<BP, 256, 0, stream>>>(src, dst, cntMatT, part);
    fill2<<<NB, 256, 0, stream>>>(cntMatT, part, rowptr, dinv, col);

    // ---- layer 1 ----
    gemm1<<<(NN + 63) / 64, 256, 0, stream>>>(x, W1, dinv, hs1);
    agg1_csr<<<NN / 4, 256, 0, stream>>>(rowptr, col, hs1, dinv, b1, h1);

    // ---- layer 2 ----
    gemm2<<<(NN + 63) / 64, 256, 0, stream>>>(h1, W2, dinv, hs2);
    agg2_csr<<<NN / 4, 256, 0, stream>>>(rowptr, col, hs2, dinv, b2, out);
}

// Round 14
// 162.248 us; speedup vs baseline: 2.0335x; 1.0978x over previous
//
#include <hip/hip_runtime.h>
#include <hip/hip_fp16.h>

#define NN 50000
#define NE 800000
#define DIN 128
#define HD 128
#define CD 64
#define NB 196        // dst buckets of 256 nodes
#define BP 128        // partition blocks
#define EPB 6250      // edges per partition block
#define NP (NB * BP)  // 25088
#define NPCHUNK ((NP + 1023) / 1024)  // 25

typedef _Float16 h2 __attribute__((ext_vector_type(2)));
typedef _Float16 h4 __attribute__((ext_vector_type(4)));
typedef _Float16 h8 __attribute__((ext_vector_type(8)));

union H8 { h8 v; h2 p[4]; };
union H4 { h4 v; h2 p[2]; };

#if defined(__has_builtin)
#if __has_builtin(__builtin_amdgcn_fdot2)
#define FDOT2(a, b, c) __builtin_amdgcn_fdot2((a), (b), (c), false)
#endif
#endif
#ifndef FDOT2
#define FDOT2(a, b, c) ((c) + (float)(a)[0] * (float)(b)[0] + (float)(a)[1] * (float)(b)[1])
#endif

// ---------------- P1: per-(bucket,block) histogram, LDS only ----------------
__global__ void __launch_bounds__(256) p1_hist(const int* __restrict__ dst, int* __restrict__ cntMatT) {
    __shared__ int hist[NB];
    int t = threadIdx.x, blk = blockIdx.x;
    if (t < NB) hist[t] = 0;
    __syncthreads();
    int base = blk * EPB;
    for (int i = base + t; i < base + EPB; i += 256)
        atomicAdd(&hist[dst[i] >> 8], 1);
    __syncthreads();
    if (t < NB) cntMatT[t * BP + blk] = hist[t];  // bucket-major
}

// ---------------- pscan: hierarchical exclusive scan of cntMatT ----------------
__global__ void __launch_bounds__(1024) pscan_a(int* __restrict__ c, int* __restrict__ sums) {
    __shared__ int wsum[16];
    int t = threadIdx.x;
    int i = blockIdx.x * 1024 + t;
    int v = (i < NP) ? c[i] : 0;
    int x = v;
#pragma unroll
    for (int off = 1; off < 64; off <<= 1) {
        int y = __shfl_up(x, off, 64);
        if ((t & 63) >= off) x += y;
    }
    int wid = t >> 6;
    if ((t & 63) == 63) wsum[wid] = x;
    __syncthreads();
    if (t < 16) {
        int s = wsum[t];
#pragma unroll
        for (int off = 1; off < 16; off <<= 1) {
            int y = __shfl_up(s, off, 16);
            if (t >= off) s += y;
        }
        wsum[t] = s;
    }
    __syncthreads();
    int basew = (wid > 0) ? wsum[wid - 1] : 0;
    int incl = basew + x;
    if (i < NP) c[i] = incl - v;
    if (t == 1023) sums[blockIdx.x] = incl;
}

__global__ void pscan_b(int* __restrict__ sums) {
    int t = threadIdx.x;
    int v = (t < NPCHUNK) ? sums[t] : 0;
    int x = v;
#pragma unroll
    for (int off = 1; off < 64; off <<= 1) {
        int y = __shfl_up(x, off, 64);
        if (t >= off) x += y;
    }
    if (t < NPCHUNK) sums[t] = x - v;
}

__global__ void pscan_c(int* __restrict__ c, const int* __restrict__ sums) {
    int i = blockIdx.x * blockDim.x + threadIdx.x;
    if (i < NP) c[i] += sums[i >> 10];
}

// ---------------- P3: partition edges into bucket-major segments ----------------
__global__ void __launch_bounds__(256) p3_scatter(const int* __restrict__ src, const int* __restrict__ dst,
                                                  const int* __restrict__ cntMatT, unsigned int* __restrict__ part) {
    __shared__ int cur[NB];
    int t = threadIdx.x, blk = blockIdx.x;
    if (t < NB) cur[t] = cntMatT[t * BP + blk];
    __syncthreads();
    int base = blk * EPB;
    for (int i = base + t; i < base + EPB; i += 256) {
        int d = dst[i];
        int b = d >> 8;
        int pos = atomicAdd(&cur[b], 1);
        part[pos] = (unsigned int)src[i] | ((unsigned int)(d & 255) << 16);
    }
}

// ---------------- fill2: per-bucket local CSR build (emits rowptr starts + dinv) ----------------
__global__ void __launch_bounds__(256) fill2(const int* __restrict__ cntMatT, const unsigned int* __restrict__ part,
                                             int* __restrict__ rowptr, float* __restrict__ dinv,
                                             int* __restrict__ col) {
    __shared__ int cnt[256];
    __shared__ int wsum[4];
    int t = threadIdx.x, b = blockIdx.x;
    int base = cntMatT[b * BP];
    int endb = (b < NB - 1) ? cntMatT[(b + 1) * BP] : NE;
    cnt[t] = 0;
    __syncthreads();
    for (int i = base + t; i < endb; i += 256)
        atomicAdd(&cnt[part[i] >> 16], 1);
    __syncthreads();
    int v = cnt[t];
    int x = v;
#pragma unroll
    for (int off = 1; off < 64; off <<= 1) {
        int y = __shfl_up(x, off, 64);
        if ((t & 63) >= off) x += y;
    }
    int wid = t >> 6;
    if ((t & 63) == 63) wsum[wid] = x;
    __syncthreads();
    if (t < 4) {
        int s = wsum[t];
#pragma unroll
        for (int off = 1; off < 4; off <<= 1) {
            int y = __shfl_up(s, off, 4);
            if (t >= off) s += y;
        }
        wsum[t] = s;
    }
    __syncthreads();
    int bw = (wid > 0) ? wsum[wid - 1] : 0;
    int start = base + bw + x - v;
    int node = b * 256 + t;
    if (node < NN) {
        rowptr[node] = start;
        dinv[node] = rsqrtf((float)(v + 2));  // +2 self loops
    }
    __syncthreads();
    cnt[t] = start;
    __syncthreads();
    for (int i = base + t; i < endb; i += 256) {
        unsigned int u = part[i];
        int pos = atomicAdd(&cnt[u >> 16], 1);
        col[pos] = (int)(u & 0xFFFFu);
    }
    if (b == NB - 1 && t == 0) rowptr[NN] = NE;
}

// ---------------- GEMM1: hs1(fp16) = dinv * (x @ W1); fp16 LDS tiles + v_dot2 ----------------
// w2[kp][c] = half2(W1[2kp][c], W1[2kp+1][c]) (32 KB); xs2[r][kp] padded 66 (16.9 KB).
__global__ void __launch_bounds__(256, 3) gemm1(const float* __restrict__ x, const float* __restrict__ W1,
                                                const float* __restrict__ dinv, __half* __restrict__ hs1) {
    __shared__ h2 w2[64 * 128];   // 32 KB
    __shared__ h2 xs2[64 * 66];   // 16.9 KB
    int t = threadIdx.x;
    int row0 = blockIdx.x * 64;
#pragma unroll
    for (int i = 0; i < 32; ++i) {          // stage W1 -> fp16 k-pairs
        int idx = t + 256 * i;
        int kp = idx >> 7, c = idx & 127;
        h2 v;
        v[0] = (_Float16)W1[(2 * kp) * HD + c];
        v[1] = (_Float16)W1[(2 * kp + 1) * HD + c];
        w2[idx] = v;
    }
#pragma unroll
    for (int i = 0; i < 16; ++i) {          // stage x-tile -> fp16 k-pairs
        int idx = t + 256 * i;
        int r = idx >> 6, kp = idx & 63;
        int gr = row0 + r; if (gr > NN - 1) gr = NN - 1;
        float2 f = ((const float2*)x)[(size_t)gr * 64 + kp];
        h2 v; v[0] = (_Float16)f.x; v[1] = (_Float16)f.y;
        xs2[r * 66 + kp] = v;
    }
    __syncthreads();

    int lane = t & 63, wv_id = t >> 6;
    int cl = lane & 15, g = lane >> 4;
    int wrow = wv_id * 16 + g * 4;
    int ca = 4 * cl, cb = 64 + 4 * cl;

    float acc[4][8];
#pragma unroll
    for (int r = 0; r < 4; ++r)
#pragma unroll
        for (int c = 0; c < 8; ++c) acc[r][c] = 0.f;

#pragma unroll 2
    for (int kq = 0; kq < 32; ++kq) {       // kq = 2 k-pairs = 4 k
        H4 xv[4];
#pragma unroll
        for (int r = 0; r < 4; ++r)
            xv[r].v = *(const h4*)&xs2[(wrow + r) * 66 + 2 * kq];
        H8 wa0, wa1, wb0, wb1;
        wa0.v = *(const h8*)&w2[(2 * kq) * 128 + ca];
        wa1.v = *(const h8*)&w2[(2 * kq + 1) * 128 + ca];
        wb0.v = *(const h8*)&w2[(2 * kq) * 128 + cb];
        wb1.v = *(const h8*)&w2[(2 * kq + 1) * 128 + cb];
#pragma unroll
        for (int r = 0; r < 4; ++r) {
            h2 x0 = xv[r].p[0];
            h2 x1 = xv[r].p[1];
#pragma unroll
            for (int cc = 0; cc < 4; ++cc) {
                acc[r][cc]     = FDOT2(x0, wa0.p[cc], acc[r][cc]);
                acc[r][cc]     = FDOT2(x1, wa1.p[cc], acc[r][cc]);
                acc[r][4 + cc] = FDOT2(x0, wb0.p[cc], acc[r][4 + cc]);
                acc[r][4 + cc] = FDOT2(x1, wb1.p[cc], acc[r][4 + cc]);
            }
        }
    }
#pragma unroll
    for (int rr = 0; rr < 4; ++rr) {
        int row = row0 + wrow + rr;
        if (row < NN) {
            float di = dinv[row];
            union { __half2 h[2]; uint2 u; } pa, pb;
            pa.h[0] = __floats2half2_rn(acc[rr][0] * di, acc[rr][1] * di);
            pa.h[1] = __floats2half2_rn(acc[rr][2] * di, acc[rr][3] * di);
            pb.h[0] = __floats2half2_rn(acc[rr][4] * di, acc[rr][5] * di);
            pb.h[1] = __floats2half2_rn(acc[rr][6] * di, acc[rr][7] * di);
            *(uint2*)&hs1[(size_t)row * HD + ca] = pa.u;
            *(uint2*)&hs1[(size_t)row * HD + cb] = pb.u;
        }
    }
}

// ---------------- GEMM2: hs2(fp16) = dinv * (h1 @ W2); fp16 LDS tiles + v_dot2 ----------------
__global__ void __launch_bounds__(256, 4) gemm2(const float* __restrict__ h1, const float* __restrict__ W2,
                                                const float* __restrict__ dinv, __half* __restrict__ hs2) {
    __shared__ h2 w2[64 * 64];    // 16 KB
    __shared__ h2 xs2[64 * 66];   // 16.9 KB
    int t = threadIdx.x;
    int row0 = blockIdx.x * 64;
#pragma unroll
    for (int i = 0; i < 16; ++i) {          // stage W2
        int idx = t + 256 * i;
        int kp = idx >> 6, c = idx & 63;
        h2 v;
        v[0] = (_Float16)W2[(2 * kp) * CD + c];
        v[1] = (_Float16)W2[(2 * kp + 1) * CD + c];
        w2[idx] = v;
    }
#pragma unroll
    for (int i = 0; i < 16; ++i) {          // stage h1-tile
        int idx = t + 256 * i;
        int r = idx >> 6, kp = idx & 63;
        int gr = row0 + r; if (gr > NN - 1) gr = NN - 1;
        float2 f = ((const float2*)h1)[(size_t)gr * 64 + kp];
        h2 v; v[0] = (_Float16)f.x; v[1] = (_Float16)f.y;
        xs2[r * 66 + kp] = v;
    }
    __syncthreads();

    int lane = t & 63, wv_id = t >> 6;
    int cl = lane & 15, g = lane >> 4;
    int wrow = wv_id * 16 + g * 4;
    int ca = 4 * cl;

    float acc[4][4];
#pragma unroll
    for (int r = 0; r < 4; ++r)
#pragma unroll
        for (int c = 0; c < 4; ++c) acc[r][c] = 0.f;

#pragma unroll 2
    for (int kq = 0; kq < 32; ++kq) {
        H4 xv[4];
#pragma unroll
        for (int r = 0; r < 4; ++r)
            xv[r].v = *(const h4*)&xs2[(wrow + r) * 66 + 2 * kq];
        H8 wa0, wa1;
        wa0.v = *(const h8*)&w2[(2 * kq) * 64 + ca];
        wa1.v = *(const h8*)&w2[(2 * kq + 1) * 64 + ca];
#pragma unroll
        for (int r = 0; r < 4; ++r) {
            h2 x0 = xv[r].p[0];
            h2 x1 = xv[r].p[1];
#pragma unroll
            for (int cc = 0; cc < 4; ++cc) {
                acc[r][cc] = FDOT2(x0, wa0.p[cc], acc[r][cc]);
                acc[r][cc] = FDOT2(x1, wa1.p[cc], acc[r][cc]);
            }
        }
    }
#pragma unroll
    for (int rr = 0; rr < 4; ++rr) {
        int row = row0 + wrow + rr;
        if (row < NN) {
            float di = dinv[row];
            union { __half2 h[2]; uint2 u; } p;
            p.h[0] = __floats2half2_rn(acc[rr][0] * di, acc[rr][1] * di);
            p.h[1] = __floats2half2_rn(acc[rr][2] * di, acc[rr][3] * di);
            *(uint2*)&hs2[(size_t)row * CD + ca] = p.u;
        }
    }
}

// ---------------- agg1: CSR gather of fp16 rows (half2/lane), unroll 8, fp32 accum ----------------
__global__ void agg1_csr(const int* __restrict__ rowptr, const int* __restrict__ col,
                         const __half* __restrict__ hs1, const float* __restrict__ dinv,
                         const float* __restrict__ b1, float* __restrict__ h1) {
    int t = threadIdx.x;
    int v = blockIdx.x * 4 + (t >> 6);
    int c2 = t & 63;
    const __half2* H = (const __half2*)hs1;  // row stride 64
    int start = rowptr[v];
    int end = rowptr[v + 1];
    float2 sf = __half22float2(H[(size_t)v * 64 + c2]);
    float ax = 2.f * sf.x, ay = 2.f * sf.y;
    int j = start;
    for (; j + 8 <= end; j += 8) {
        int s0 = col[j], s1 = col[j + 1], s2 = col[j + 2], s3 = col[j + 3];
        int s4 = col[j + 4], s5 = col[j + 5], s6 = col[j + 6], s7 = col[j + 7];
        float2 v0 = __half22float2(H[(size_t)s0 * 64 + c2]);
        float2 v1 = __half22float2(H[(size_t)s1 * 64 + c2]);
        float2 v2 = __half22float2(H[(size_t)s2 * 64 + c2]);
        float2 v3 = __half22float2(H[(size_t)s3 * 64 + c2]);
        float2 v4 = __half22float2(H[(size_t)s4 * 64 + c2]);
        float2 v5 = __half22float2(H[(size_t)s5 * 64 + c2]);
        float2 v6 = __half22float2(H[(size_t)s6 * 64 + c2]);
        float2 v7 = __half22float2(H[(size_t)s7 * 64 + c2]);
        ax += ((v0.x + v1.x) + (v2.x + v3.x)) + ((v4.x + v5.x) + (v6.x + v7.x));
        ay += ((v0.y + v1.y) + (v2.y + v3.y)) + ((v4.y + v5.y) + (v6.y + v7.y));
    }
    for (; j < end; ++j) {
        float2 u = __half22float2(H[(size_t)col[j] * 64 + c2]);
        ax += u.x; ay += u.y;
    }
    float di = dinv[v];
    int c = c2 * 2;
    float2 r;
    r.x = fmaxf(di * ax + b1[c], 0.f);
    r.y = fmaxf(di * ay + b1[c + 1], 0.f);
    ((float2*)h1)[(size_t)v * 64 + c2] = r;
}

// ---------------- agg2: CSR gather of fp16 rows + bias + log_softmax, unroll 8 ----------------
__global__ void agg2_csr(const int* __restrict__ rowptr, const int* __restrict__ col,
                         const __half* __restrict__ hs2, const float* __restrict__ dinv,
                         const float* __restrict__ b2, float* __restrict__ out) {
    int t = threadIdx.x;
    int v = blockIdx.x * 4 + (t >> 6);
    int c = t & 63;
    int start = rowptr[v];
    int end = rowptr[v + 1];
    float acc = 2.f * __half2float(hs2[(size_t)v * CD + c]);
    int j = start;
    for (; j + 8 <= end; j += 8) {
        int s0 = col[j], s1 = col[j + 1], s2 = col[j + 2], s3 = col[j + 3];
        int s4 = col[j + 4], s5 = col[j + 5], s6 = col[j + 6], s7 = col[j + 7];
        float a0 = __half2float(hs2[(size_t)s0 * CD + c]), a1 = __half2float(hs2[(size_t)s1 * CD + c]);
        float a2 = __half2float(hs2[(size_t)s2 * CD + c]), a3 = __half2float(hs2[(size_t)s3 * CD + c]);
        float a4 = __half2float(hs2[(size_t)s4 * CD + c]), a5 = __half2float(hs2[(size_t)s5 * CD + c]);
        float a6 = __half2float(hs2[(size_t)s6 * CD + c]), a7 = __half2float(hs2[(size_t)s7 * CD + c]);
        acc += ((a0 + a1) + (a2 + a3)) + ((a4 + a5) + (a6 + a7));
    }
    for (; j < end; ++j) acc += __half2float(hs2[(size_t)col[j] * CD + c]);
    float o = dinv[v] * acc + b2[c];
    float m = o;
#pragma unroll
    for (int off = 32; off >= 1; off >>= 1) m = fmaxf(m, __shfl_xor(m, off, 64));
    float ex = __expf(o - m);
    float s = ex;
#pragma unroll
    for (int off = 32; off >= 1; off >>= 1) s += __shfl_xor(s, off, 64);
    out[(size_t)v * CD + c] = o - m - __logf(s);
}

extern "C" void kernel_launch(void* const* d_in, const int* in_sizes, int n_in,
                              void* d_out, int out_size, void* d_ws, size_t ws_size,
                              hipStream_t stream) {
    const float* x  = (const float*)d_in[0];
    const int*   ei = (const int*)d_in[1];   // [2, E] int32
    const float* W1 = (const float*)d_in[2];
    const float* b1 = (const float*)d_in[3];
    const float* W2 = (const float*)d_in[4];
    const float* b2 = (const float*)d_in[5];
    float* out = (float*)d_out;

    const int* src = ei;
    const int* dst = ei + NE;

    float* ws = (float*)d_ws;
    float*        dinv    = ws;                              // NN floats
    int*          rowptr  = (int*)(ws + 65536);              // NN+1 ints
    int*          col     = (int*)(ws + 131072);             // NE ints -> 931072
    int*          cntMatT = (int*)(ws + 931136);             // NP ints
    int*          psums   = (int*)(ws + 956224);             // 25 ints
    unsigned int* part    = (unsigned int*)(ws + 960000);    // NE u32 -> 1760000
    __half*       hs1     = (__half*)(ws + 1760000);         // NN*HD halves
    float*        h1      = ws + 4960000;                    // NN*HD floats
    __half*       hs2     = hs1;                             // reuse

    // ---- CSR build: partition -> local fill (no global atomics anywhere) ----
    p1_hist<<<BP, 256, 0, stream>>>(dst, cntMatT);
    pscan_a<<<NPCHUNK, 1024, 0, stream>>>(cntMatT, psums);
    pscan_b<<<1, 64, 0, stream>>>(psums);
    pscan_c<<<(NP + 255) / 256, 256, 0, stream>>>(cntMatT, psums);
    p3_scatter<<<BP, 256, 0, stream>>>(src, dst, cntMatT, part);
    fill2<<<NB, 256, 0, stream>>>(cntMatT, part, rowptr, dinv, col);

    // ---- layer 1 ----
    gemm1<<<(NN + 63) / 64, 256, 0, stream>>>(x, W1, dinv, hs1);
    agg1_csr<<<NN / 4, 256, 0, stream>>>(rowptr, col, hs1, dinv, b1, h1);

    // ---- layer 2 ----
    gemm2<<<(NN + 63) / 64, 256, 0, stream>>>(h1, W2, dinv, hs2);
    agg2_csr<<<NN / 4, 256, 0, stream>>>(rowptr, col, hs2, dinv, b2, out);
}

// Round 15
// 151.774 us; speedup vs baseline: 2.1739x; 1.0690x over previous
//
#include <hip/hip_runtime.h>
#include <hip/hip_fp16.h>

#define NN 50000
#define NE 800000
#define DIN 128
#define HD 128
#define CD 64
#define NB 196        // dst buckets of 256 nodes
#define BP 128        // partition blocks
#define EPB 6250      // edges per partition block
#define NP (NB * BP)  // 25088
#define NPCHUNK ((NP + 1023) / 1024)  // 25
#define G1B 782       // gemm1 blocks (ceil(50000/64))

typedef _Float16 h2 __attribute__((ext_vector_type(2)));
typedef _Float16 h4 __attribute__((ext_vector_type(4)));
typedef _Float16 h8 __attribute__((ext_vector_type(8)));

union H8 { h8 v; h2 p[4]; };
union H4 { h4 v; h2 p[2]; };

#if defined(__has_builtin)
#if __has_builtin(__builtin_amdgcn_fdot2)
#define FDOT2(a, b, c) __builtin_amdgcn_fdot2((a), (b), (c), false)
#endif
#endif
#ifndef FDOT2
#define FDOT2(a, b, c) ((c) + (float)(a)[0] * (float)(b)[0] + (float)(a)[1] * (float)(b)[1])
#endif

// ---------------- gp1: gemm1 (unscaled, no dinv dep) fused with p1_hist ----------------
// blocks [0, G1B): hs1(fp16) = x @ W1 ; blocks [G1B, G1B+BP): per-(bucket,block) histogram
__global__ void __launch_bounds__(256) gp1(const float* __restrict__ x, const float* __restrict__ W1,
                                           __half* __restrict__ hs1,
                                           const int* __restrict__ dst, int* __restrict__ cntMatT) {
    __shared__ __align__(16) char smem[64 * 128 * 4 + 64 * 66 * 4];  // 48.5 KB
    if (blockIdx.x >= G1B) {  // ---- p1_hist ----
        int* hist = (int*)smem;
        int t = threadIdx.x, blk = blockIdx.x - G1B;
        if (t < NB) hist[t] = 0;
        __syncthreads();
        int base = blk * EPB;
        for (int i = base + t; i < base + EPB; i += 256)
            atomicAdd(&hist[dst[i] >> 8], 1);
        __syncthreads();
        if (t < NB) cntMatT[t * BP + blk] = hist[t];  // bucket-major
        return;
    }
    // ---- gemm1 ----
    h2* w2 = (h2*)smem;                    // [64 kp][128 c]
    h2* xs2 = (h2*)(smem + 64 * 128 * 4);  // [64 r][66 kp]
    int t = threadIdx.x;
    int row0 = blockIdx.x * 64;
#pragma unroll
    for (int i = 0; i < 32; ++i) {
        int idx = t + 256 * i;
        int kp = idx >> 7, c = idx & 127;
        h2 v;
        v[0] = (_Float16)W1[(2 * kp) * HD + c];
        v[1] = (_Float16)W1[(2 * kp + 1) * HD + c];
        w2[idx] = v;
    }
#pragma unroll
    for (int i = 0; i < 16; ++i) {
        int idx = t + 256 * i;
        int r = idx >> 6, kp = idx & 63;
        int gr = row0 + r; if (gr > NN - 1) gr = NN - 1;
        float2 f = ((const float2*)x)[(size_t)gr * 64 + kp];
        h2 v; v[0] = (_Float16)f.x; v[1] = (_Float16)f.y;
        xs2[r * 66 + kp] = v;
    }
    __syncthreads();

    int lane = t & 63, wv_id = t >> 6;
    int cl = lane & 15, g = lane >> 4;
    int wrow = wv_id * 16 + g * 4;
    int ca = 4 * cl, cb = 64 + 4 * cl;

    float acc[4][8];
#pragma unroll
    for (int r = 0; r < 4; ++r)
#pragma unroll
        for (int c = 0; c < 8; ++c) acc[r][c] = 0.f;

#pragma unroll 2
    for (int kq = 0; kq < 32; ++kq) {
        H4 xv[4];
#pragma unroll
        for (int r = 0; r < 4; ++r)
            xv[r].v = *(const h4*)&xs2[(wrow + r) * 66 + 2 * kq];
        H8 wa0, wa1, wb0, wb1;
        wa0.v = *(const h8*)&w2[(2 * kq) * 128 + ca];
        wa1.v = *(const h8*)&w2[(2 * kq + 1) * 128 + ca];
        wb0.v = *(const h8*)&w2[(2 * kq) * 128 + cb];
        wb1.v = *(const h8*)&w2[(2 * kq + 1) * 128 + cb];
#pragma unroll
        for (int r = 0; r < 4; ++r) {
            h2 x0 = xv[r].p[0];
            h2 x1 = xv[r].p[1];
#pragma unroll
            for (int cc = 0; cc < 4; ++cc) {
                acc[r][cc]     = FDOT2(x0, wa0.p[cc], acc[r][cc]);
                acc[r][cc]     = FDOT2(x1, wa1.p[cc], acc[r][cc]);
                acc[r][4 + cc] = FDOT2(x0, wb0.p[cc], acc[r][4 + cc]);
                acc[r][4 + cc] = FDOT2(x1, wb1.p[cc], acc[r][4 + cc]);
            }
        }
    }
#pragma unroll
    for (int rr = 0; rr < 4; ++rr) {
        int row = row0 + wrow + rr;
        if (row < NN) {
            union { __half2 h[2]; uint2 u; } pa, pb;
            pa.h[0] = __floats2half2_rn(acc[rr][0], acc[rr][1]);
            pa.h[1] = __floats2half2_rn(acc[rr][2], acc[rr][3]);
            pb.h[0] = __floats2half2_rn(acc[rr][4], acc[rr][5]);
            pb.h[1] = __floats2half2_rn(acc[rr][6], acc[rr][7]);
            *(uint2*)&hs1[(size_t)row * HD + ca] = pa.u;
            *(uint2*)&hs1[(size_t)row * HD + cb] = pb.u;
        }
    }
}

// ---------------- pscan_a: chunk-local exclusive scan + chunk totals ----------------
__global__ void __launch_bounds__(1024) pscan_a(int* __restrict__ c, int* __restrict__ sums) {
    __shared__ int wsum[16];
    int t = threadIdx.x;
    int i = blockIdx.x * 1024 + t;
    int v = (i < NP) ? c[i] : 0;
    int x = v;
#pragma unroll
    for (int off = 1; off < 64; off <<= 1) {
        int y = __shfl_up(x, off, 64);
        if ((t & 63) >= off) x += y;
    }
    int wid = t >> 6;
    if ((t & 63) == 63) wsum[wid] = x;
    __syncthreads();
    if (t < 16) {
        int s = wsum[t];
#pragma unroll
        for (int off = 1; off < 16; off <<= 1) {
            int y = __shfl_up(s, off, 16);
            if (t >= off) s += y;
        }
        wsum[t] = s;
    }
    __syncthreads();
    int basew = (wid > 0) ? wsum[wid - 1] : 0;
    int incl = basew + x;
    if (i < NP) c[i] = incl - v;  // chunk-local exclusive
    if (t == 1023) sums[blockIdx.x] = incl;
}

// ---------------- P3: partition edges (applies chunk bases locally) ----------------
__global__ void __launch_bounds__(256) p3_scatter(const int* __restrict__ src, const int* __restrict__ dst,
                                                  const int* __restrict__ cntMatT, const int* __restrict__ sums,
                                                  unsigned int* __restrict__ part) {
    __shared__ int cur[NB];
    __shared__ int sbase[NPCHUNK];
    int t = threadIdx.x, blk = blockIdx.x;
    if (t < 32) {
        int v = (t < NPCHUNK) ? sums[t] : 0;
        int x = v;
#pragma unroll
        for (int off = 1; off < 32; off <<= 1) {
            int y = __shfl_up(x, off, 32);
            if (t >= off) x += y;
        }
        if (t < NPCHUNK) sbase[t] = x - v;  // exclusive chunk bases
    }
    __syncthreads();
    if (t < NB) {
        int i = t * BP + blk;
        cur[t] = cntMatT[i] + sbase[i >> 10];
    }
    __syncthreads();
    int base = blk * EPB;
    for (int i = base + t; i < base + EPB; i += 256) {
        int d = dst[i];
        int b = d >> 8;
        int pos = atomicAdd(&cur[b], 1);
        part[pos] = (unsigned int)src[i] | ((unsigned int)(d & 255) << 16);
    }
}

// ---------------- fill2: per-bucket CSR build (emits rowptr starts + dinv + col) ----------------
__global__ void __launch_bounds__(256) fill2(const int* __restrict__ cntMatT, const int* __restrict__ sums,
                                             const unsigned int* __restrict__ part,
                                             int* __restrict__ rowptr, float* __restrict__ dinv,
                                             int* __restrict__ col) {
    __shared__ int cnt[256];
    __shared__ int wsum[4];
    __shared__ int sbase[NPCHUNK];
    int t = threadIdx.x, b = blockIdx.x;
    if (t < 32) {
        int v = (t < NPCHUNK) ? sums[t] : 0;
        int x = v;
#pragma unroll
        for (int off = 1; off < 32; off <<= 1) {
            int y = __shfl_up(x, off, 32);
            if (t >= off) x += y;
        }
        if (t < NPCHUNK) sbase[t] = x - v;
    }
    cnt[t] = 0;
    __syncthreads();
    int i0 = b * BP;
    int base = cntMatT[i0] + sbase[i0 >> 10];
    int endb = (b < NB - 1) ? (cntMatT[i0 + BP] + sbase[(i0 + BP) >> 10]) : NE;
    for (int i = base + t; i < endb; i += 256)
        atomicAdd(&cnt[part[i] >> 16], 1);
    __syncthreads();
    int v = cnt[t];
    int x = v;
#pragma unroll
    for (int off = 1; off < 64; off <<= 1) {
        int y = __shfl_up(x, off, 64);
        if ((t & 63) >= off) x += y;
    }
    int wid = t >> 6;
    if ((t & 63) == 63) wsum[wid] = x;
    __syncthreads();
    if (t < 4) {
        int s = wsum[t];
#pragma unroll
        for (int off = 1; off < 4; off <<= 1) {
            int y = __shfl_up(s, off, 4);
            if (t >= off) s += y;
        }
        wsum[t] = s;
    }
    __syncthreads();
    int bw = (wid > 0) ? wsum[wid - 1] : 0;
    int start = base + bw + x - v;
    int node = b * 256 + t;
    if (node < NN) {
        rowptr[node] = start;
        dinv[node] = rsqrtf((float)(v + 2));  // +2 self loops
    }
    __syncthreads();
    cnt[t] = start;
    __syncthreads();
    for (int i = base + t; i < endb; i += 256) {
        unsigned int u = part[i];
        int pos = atomicAdd(&cnt[u >> 16], 1);
        col[pos] = (int)(u & 0xFFFFu);
    }
    if (b == NB - 1 && t == 0) rowptr[NN] = NE;
}

// ---------------- agg1: gather unscaled fp16 rows, scale by dinv[s]; h1 out fp16 ----------------
__global__ void agg1_csr(const int* __restrict__ rowptr, const int* __restrict__ col,
                         const __half* __restrict__ hs1, const float* __restrict__ dinv,
                         const float* __restrict__ b1, __half* __restrict__ h1h) {
    int t = threadIdx.x;
    int v = blockIdx.x * 4 + (t >> 6);
    int c2 = t & 63;
    const __half2* H = (const __half2*)hs1;  // row stride 64
    int start = rowptr[v];
    int end = rowptr[v + 1];
    float dv = dinv[v];
    float2 sf = __half22float2(H[(size_t)v * 64 + c2]);
    float ax = 2.f * dv * sf.x, ay = 2.f * dv * sf.y;
    int j = start;
    for (; j + 8 <= end; j += 8) {
        int s0 = col[j], s1 = col[j + 1], s2 = col[j + 2], s3 = col[j + 3];
        int s4 = col[j + 4], s5 = col[j + 5], s6 = col[j + 6], s7 = col[j + 7];
        float d0 = dinv[s0], d1 = dinv[s1], d2 = dinv[s2], d3 = dinv[s3];
        float d4 = dinv[s4], d5 = dinv[s5], d6 = dinv[s6], d7 = dinv[s7];
        float2 v0 = __half22float2(H[(size_t)s0 * 64 + c2]);
        float2 v1 = __half22float2(H[(size_t)s1 * 64 + c2]);
        float2 v2 = __half22float2(H[(size_t)s2 * 64 + c2]);
        float2 v3 = __half22float2(H[(size_t)s3 * 64 + c2]);
        float2 v4 = __half22float2(H[(size_t)s4 * 64 + c2]);
        float2 v5 = __half22float2(H[(size_t)s5 * 64 + c2]);
        float2 v6 = __half22float2(H[(size_t)s6 * 64 + c2]);
        float2 v7 = __half22float2(H[(size_t)s7 * 64 + c2]);
        ax += d0 * v0.x + d1 * v1.x + d2 * v2.x + d3 * v3.x
            + d4 * v4.x + d5 * v5.x + d6 * v6.x + d7 * v7.x;
        ay += d0 * v0.y + d1 * v1.y + d2 * v2.y + d3 * v3.y
            + d4 * v4.y + d5 * v5.y + d6 * v6.y + d7 * v7.y;
    }
    for (; j < end; ++j) {
        int s = col[j];
        float ds = dinv[s];
        float2 u = __half22float2(H[(size_t)s * 64 + c2]);
        ax += ds * u.x; ay += ds * u.y;
    }
    int c = c2 * 2;
    float rx = fmaxf(dv * ax + b1[c], 0.f);
    float ry = fmaxf(dv * ay + b1[c + 1], 0.f);
    ((__half2*)h1h)[(size_t)v * 64 + c2] = __floats2half2_rn(rx, ry);
}

// ---------------- GEMM2: hs2(fp16) = h1(fp16) @ W2 (unscaled) ----------------
__global__ void __launch_bounds__(256, 4) gemm2(const __half* __restrict__ h1h, const float* __restrict__ W2,
                                                __half* __restrict__ hs2) {
    __shared__ h2 w2[64 * 64];    // 16 KB
    __shared__ h2 xs2[64 * 66];   // 16.9 KB
    int t = threadIdx.x;
    int row0 = blockIdx.x * 64;
    const h2* H = (const h2*)h1h;
#pragma unroll
    for (int i = 0; i < 16; ++i) {
        int idx = t + 256 * i;
        int kp = idx >> 6, c = idx & 63;
        h2 v;
        v[0] = (_Float16)W2[(2 * kp) * CD + c];
        v[1] = (_Float16)W2[(2 * kp + 1) * CD + c];
        w2[idx] = v;
    }
#pragma unroll
    for (int i = 0; i < 16; ++i) {
        int idx = t + 256 * i;
        int r = idx >> 6, kp = idx & 63;
        int gr = row0 + r; if (gr > NN - 1) gr = NN - 1;
        xs2[r * 66 + kp] = H[(size_t)gr * 64 + kp];  // fp16 passthrough
    }
    __syncthreads();

    int lane = t & 63, wv_id = t >> 6;
    int cl = lane & 15, g = lane >> 4;
    int wrow = wv_id * 16 + g * 4;
    int ca = 4 * cl;

    float acc[4][4];
#pragma unroll
    for (int r = 0; r < 4; ++r)
#pragma unroll
        for (int c = 0; c < 4; ++c) acc[r][c] = 0.f;

#pragma unroll 2
    for (int kq = 0; kq < 32; ++kq) {
        H4 xv[4];
#pragma unroll
        for (int r = 0; r < 4; ++r)
            xv[r].v = *(const h4*)&xs2[(wrow + r) * 66 + 2 * kq];
        H8 wa0, wa1;
        wa0.v = *(const h8*)&w2[(2 * kq) * 64 + ca];
        wa1.v = *(const h8*)&w2[(2 * kq + 1) * 64 + ca];
#pragma unroll
        for (int r = 0; r < 4; ++r) {
            h2 x0 = xv[r].p[0];
            h2 x1 = xv[r].p[1];
#pragma unroll
            for (int cc = 0; cc < 4; ++cc) {
                acc[r][cc] = FDOT2(x0, wa0.p[cc], acc[r][cc]);
                acc[r][cc] = FDOT2(x1, wa1.p[cc], acc[r][cc]);
            }
        }
    }
#pragma unroll
    for (int rr = 0; rr < 4; ++rr) {
        int row = row0 + wrow + rr;
        if (row < NN) {
            union { __half2 h[2]; uint2 u; } p;
            p.h[0] = __floats2half2_rn(acc[rr][0], acc[rr][1]);
            p.h[1] = __floats2half2_rn(acc[rr][2], acc[rr][3]);
            *(uint2*)&hs2[(size_t)row * CD + ca] = p.u;
        }
    }
}

// ---------------- agg2: gather unscaled fp16 + dinv[s] scale + bias + log_softmax ----------------
__global__ void agg2_csr(const int* __restrict__ rowptr, const int* __restrict__ col,
                         const __half* __restrict__ hs2, const float* __restrict__ dinv,
                         const float* __restrict__ b2, float* __restrict__ out) {
    int t = threadIdx.x;
    int v = blockIdx.x * 4 + (t >> 6);
    int c = t & 63;
    int start = rowptr[v];
    int end = rowptr[v + 1];
    float dv = dinv[v];
    float acc = 2.f * dv * __half2float(hs2[(size_t)v * CD + c]);
    int j = start;
    for (; j + 8 <= end; j += 8) {
        int s0 = col[j], s1 = col[j + 1], s2 = col[j + 2], s3 = col[j + 3];
        int s4 = col[j + 4], s5 = col[j + 5], s6 = col[j + 6], s7 = col[j + 7];
        float d0 = dinv[s0], d1 = dinv[s1], d2 = dinv[s2], d3 = dinv[s3];
        float d4 = dinv[s4], d5 = dinv[s5], d6 = dinv[s6], d7 = dinv[s7];
        float a0 = __half2float(hs2[(size_t)s0 * CD + c]), a1 = __half2float(hs2[(size_t)s1 * CD + c]);
        float a2 = __half2float(hs2[(size_t)s2 * CD + c]), a3 = __half2float(hs2[(size_t)s3 * CD + c]);
        float a4 = __half2float(hs2[(size_t)s4 * CD + c]), a5 = __half2float(hs2[(size_t)s5 * CD + c]);
        float a6 = __half2float(hs2[(size_t)s6 * CD + c]), a7 = __half2float(hs2[(size_t)s7 * CD + c]);
        acc += d0 * a0 + d1 * a1 + d2 * a2 + d3 * a3 + d4 * a4 + d5 * a5 + d6 * a6 + d7 * a7;
    }
    for (; j < end; ++j) {
        int s = col[j];
        acc += dinv[s] * __half2float(hs2[(size_t)s * CD + c]);
    }
    float o = dv * acc + b2[c];
    float m = o;
#pragma unroll
    for (int off = 32; off >= 1; off >>= 1) m = fmaxf(m, __shfl_xor(m, off, 64));
    float ex = __expf(o - m);
    float s = ex;
#pragma unroll
    for (int off = 32; off >= 1; off >>= 1) s += __shfl_xor(s, off, 64);
    out[(size_t)v * CD + c] = o - m - __logf(s);
}

extern "C" void kernel_launch(void* const* d_in, const int* in_sizes, int n_in,
                              void* d_out, int out_size, void* d_ws, size_t ws_size,
                              hipStream_t stream) {
    const float* x  = (const float*)d_in[0];
    const int*   ei = (const int*)d_in[1];   // [2, E] int32
    const float* W1 = (const float*)d_in[2];
    const float* b1 = (const float*)d_in[3];
    const float* W2 = (const float*)d_in[4];
    const float* b2 = (const float*)d_in[5];
    float* out = (float*)d_out;

    const int* src = ei;
    const int* dst = ei + NE;

    float* ws = (float*)d_ws;
    float*        dinv    = ws;                              // NN floats
    int*          rowptr  = (int*)(ws + 65536);              // NN+1 ints
    int*          col     = (int*)(ws + 131072);             // NE ints -> 931072
    int*          cntMatT = (int*)(ws + 931136);             // NP ints
    int*          psums   = (int*)(ws + 956224);             // 25 ints
    unsigned int* part    = (unsigned int*)(ws + 960000);    // NE u32 -> 1760000
    __half*       hs1     = (__half*)(ws + 1760000);         // NN*HD halves -> 4960000
    __half*       h1h     = (__half*)(ws + 4960000);         // NN*HD halves -> 8160000
    __half*       hs2     = hs1;                             // reuse (hs1 dead after agg1)

    // 1) gemm1 (unscaled) fused with p1_hist
    gp1<<<G1B + BP, 256, 0, stream>>>(x, W1, hs1, dst, cntMatT);
    // 2) chunk-local scan of the (bucket,block) count matrix
    pscan_a<<<NPCHUNK, 1024, 0, stream>>>(cntMatT, psums);
    // 3) partition edges into bucket-major segments (applies chunk bases locally)
    p3_scatter<<<BP, 256, 0, stream>>>(src, dst, cntMatT, psums, part);
    // 4) per-bucket CSR build (rowptr starts + dinv + col)
    fill2<<<NB, 256, 0, stream>>>(cntMatT, psums, part, rowptr, dinv, col);
    // 5) layer-1 aggregation (+ReLU), h1 in fp16
    agg1_csr<<<NN / 4, 256, 0, stream>>>(rowptr, col, hs1, dinv, b1, h1h);
    // 6) layer-2 dense transform (fp16 in/out, unscaled)
    gemm2<<<(NN + 63) / 64, 256, 0, stream>>>(h1h, W2, hs2);
    // 7) layer-2 aggregation + bias + log_softmax
    agg2_csr<<<NN / 4, 256, 0, stream>>>(rowptr, col, hs2, dinv, b2, out);
}

// Round 16
// 138.786 us; speedup vs baseline: 2.3773x; 1.0936x over previous
//
#include <hip/hip_runtime.h>
#include <hip/hip_fp16.h>

#define NN 50000
#define NE 800000
#define DIN 128
#define HD 128
#define CD 64
#define NB 196        // dst buckets of 256 nodes
#define BP 128        // partition blocks
#define EPB 6250      // edges per partition block
#define NP (NB * BP)  // 25088
#define NPCHUNK ((NP + 1023) / 1024)  // 25
#define G1B 782       // gemm1 blocks (ceil(50000/64))

typedef _Float16 h2 __attribute__((ext_vector_type(2)));
typedef _Float16 h4 __attribute__((ext_vector_type(4)));
typedef _Float16 h8 __attribute__((ext_vector_type(8)));

union H8 { h8 v; h2 p[4]; };
union H4 { h4 v; h2 p[2]; };

#if defined(__has_builtin)
#if __has_builtin(__builtin_amdgcn_fdot2)
#define FDOT2(a, b, c) __builtin_amdgcn_fdot2((a), (b), (c), false)
#endif
#endif
#ifndef FDOT2
#define FDOT2(a, b, c) ((c) + (float)(a)[0] * (float)(b)[0] + (float)(a)[1] * (float)(b)[1])
#endif

// ---------------- gp1: gemm1 (unscaled) fused with p1_hist ----------------
__global__ void __launch_bounds__(256) gp1(const float* __restrict__ x, const float* __restrict__ W1,
                                           __half* __restrict__ hs1,
                                           const int* __restrict__ dst, int* __restrict__ cntMatT) {
    __shared__ __align__(16) char smem[64 * 128 * 4 + 64 * 66 * 4];  // 48.5 KB
    if (blockIdx.x >= G1B) {  // ---- p1_hist ----
        int* hist = (int*)smem;
        int t = threadIdx.x, blk = blockIdx.x - G1B;
        if (t < NB) hist[t] = 0;
        __syncthreads();
        int base = blk * EPB;
        for (int i = base + t; i < base + EPB; i += 256)
            atomicAdd(&hist[dst[i] >> 8], 1);
        __syncthreads();
        if (t < NB) cntMatT[t * BP + blk] = hist[t];  // bucket-major
        return;
    }
    // ---- gemm1 ----
    h2* w2 = (h2*)smem;                    // [64 kp][128 c]
    h2* xs2 = (h2*)(smem + 64 * 128 * 4);  // [64 r][66 kp]
    int t = threadIdx.x;
    int row0 = blockIdx.x * 64;
#pragma unroll
    for (int i = 0; i < 32; ++i) {
        int idx = t + 256 * i;
        int kp = idx >> 7, c = idx & 127;
        h2 v;
        v[0] = (_Float16)W1[(2 * kp) * HD + c];
        v[1] = (_Float16)W1[(2 * kp + 1) * HD + c];
        w2[idx] = v;
    }
#pragma unroll
    for (int i = 0; i < 16; ++i) {
        int idx = t + 256 * i;
        int r = idx >> 6, kp = idx & 63;
        int gr = row0 + r; if (gr > NN - 1) gr = NN - 1;
        float2 f = ((const float2*)x)[(size_t)gr * 64 + kp];
        h2 v; v[0] = (_Float16)f.x; v[1] = (_Float16)f.y;
        xs2[r * 66 + kp] = v;
    }
    __syncthreads();

    int lane = t & 63, wv_id = t >> 6;
    int cl = lane & 15, g = lane >> 4;
    int wrow = wv_id * 16 + g * 4;
    int ca = 4 * cl, cb = 64 + 4 * cl;

    float acc[4][8];
#pragma unroll
    for (int r = 0; r < 4; ++r)
#pragma unroll
        for (int c = 0; c < 8; ++c) acc[r][c] = 0.f;

#pragma unroll 2
    for (int kq = 0; kq < 32; ++kq) {
        H4 xv[4];
#pragma unroll
        for (int r = 0; r < 4; ++r)
            xv[r].v = *(const h4*)&xs2[(wrow + r) * 66 + 2 * kq];
        H8 wa0, wa1, wb0, wb1;
        wa0.v = *(const h8*)&w2[(2 * kq) * 128 + ca];
        wa1.v = *(const h8*)&w2[(2 * kq + 1) * 128 + ca];
        wb0.v = *(const h8*)&w2[(2 * kq) * 128 + cb];
        wb1.v = *(const h8*)&w2[(2 * kq + 1) * 128 + cb];
#pragma unroll
        for (int r = 0; r < 4; ++r) {
            h2 x0 = xv[r].p[0];
            h2 x1 = xv[r].p[1];
#pragma unroll
            for (int cc = 0; cc < 4; ++cc) {
                acc[r][cc]     = FDOT2(x0, wa0.p[cc], acc[r][cc]);
                acc[r][cc]     = FDOT2(x1, wa1.p[cc], acc[r][cc]);
                acc[r][4 + cc] = FDOT2(x0, wb0.p[cc], acc[r][4 + cc]);
                acc[r][4 + cc] = FDOT2(x1, wb1.p[cc], acc[r][4 + cc]);
            }
        }
    }
#pragma unroll
    for (int rr = 0; rr < 4; ++rr) {
        int row = row0 + wrow + rr;
        if (row < NN) {
            union { __half2 h[2]; uint2 u; } pa, pb;
            pa.h[0] = __floats2half2_rn(acc[rr][0], acc[rr][1]);
            pa.h[1] = __floats2half2_rn(acc[rr][2], acc[rr][3]);
            pb.h[0] = __floats2half2_rn(acc[rr][4], acc[rr][5]);
            pb.h[1] = __floats2half2_rn(acc[rr][6], acc[rr][7]);
            *(uint2*)&hs1[(size_t)row * HD + ca] = pa.u;
            *(uint2*)&hs1[(size_t)row * HD + cb] = pb.u;
        }
    }
}

// ---------------- pscan_a: chunk-local exclusive scan + chunk totals ----------------
__global__ void __launch_bounds__(1024) pscan_a(int* __restrict__ c, int* __restrict__ sums) {
    __shared__ int wsum[16];
    int t = threadIdx.x;
    int i = blockIdx.x * 1024 + t;
    int v = (i < NP) ? c[i] : 0;
    int x = v;
#pragma unroll
    for (int off = 1; off < 64; off <<= 1) {
        int y = __shfl_up(x, off, 64);
        if ((t & 63) >= off) x += y;
    }
    int wid = t >> 6;
    if ((t & 63) == 63) wsum[wid] = x;
    __syncthreads();
    if (t < 16) {
        int s = wsum[t];
#pragma unroll
        for (int off = 1; off < 16; off <<= 1) {
            int y = __shfl_up(s, off, 16);
            if (t >= off) s += y;
        }
        wsum[t] = s;
    }
    __syncthreads();
    int basew = (wid > 0) ? wsum[wid - 1] : 0;
    int incl = basew + x;
    if (i < NP) c[i] = incl - v;  // chunk-local exclusive
    if (t == 1023) sums[blockIdx.x] = incl;
}

// ---------------- P3: partition edges (applies chunk bases locally) ----------------
__global__ void __launch_bounds__(256) p3_scatter(const int* __restrict__ src, const int* __restrict__ dst,
                                                  const int* __restrict__ cntMatT, const int* __restrict__ sums,
                                                  unsigned int* __restrict__ part) {
    __shared__ int cur[NB];
    __shared__ int sbase[NPCHUNK];
    int t = threadIdx.x, blk = blockIdx.x;
    if (t < 32) {
        int v = (t < NPCHUNK) ? sums[t] : 0;
        int x = v;
#pragma unroll
        for (int off = 1; off < 32; off <<= 1) {
            int y = __shfl_up(x, off, 32);
            if (t >= off) x += y;
        }
        if (t < NPCHUNK) sbase[t] = x - v;  // exclusive chunk bases
    }
    __syncthreads();
    if (t < NB) {
        int i = t * BP + blk;
        cur[t] = cntMatT[i] + sbase[i >> 10];
    }
    __syncthreads();
    int base = blk * EPB;
    for (int i = base + t; i < base + EPB; i += 256) {
        int d = dst[i];
        int b = d >> 8;
        int pos = atomicAdd(&cur[b], 1);
        part[pos] = (unsigned int)src[i] | ((unsigned int)(d & 255) << 16);
    }
}

// ---------------- fill2: per-bucket CSR build (emits rowptr starts + dinv + col) ----------------
__global__ void __launch_bounds__(256) fill2(const int* __restrict__ cntMatT, const int* __restrict__ sums,
                                             const unsigned int* __restrict__ part,
                                             int* __restrict__ rowptr, float* __restrict__ dinv,
                                             int* __restrict__ col) {
    __shared__ int cnt[256];
    __shared__ int wsum[4];
    __shared__ int sbase[NPCHUNK];
    int t = threadIdx.x, b = blockIdx.x;
    if (t < 32) {
        int v = (t < NPCHUNK) ? sums[t] : 0;
        int x = v;
#pragma unroll
        for (int off = 1; off < 32; off <<= 1) {
            int y = __shfl_up(x, off, 32);
            if (t >= off) x += y;
        }
        if (t < NPCHUNK) sbase[t] = x - v;
    }
    cnt[t] = 0;
    __syncthreads();
    int i0 = b * BP;
    int base = cntMatT[i0] + sbase[i0 >> 10];
    int endb = (b < NB - 1) ? (cntMatT[i0 + BP] + sbase[(i0 + BP) >> 10]) : NE;
    for (int i = base + t; i < endb; i += 256)
        atomicAdd(&cnt[part[i] >> 16], 1);
    __syncthreads();
    int v = cnt[t];
    int x = v;
#pragma unroll
    for (int off = 1; off < 64; off <<= 1) {
        int y = __shfl_up(x, off, 64);
        if ((t & 63) >= off) x += y;
    }
    int wid = t >> 6;
    if ((t & 63) == 63) wsum[wid] = x;
    __syncthreads();
    if (t < 4) {
        int s = wsum[t];
#pragma unroll
        for (int off = 1; off < 4; off <<= 1) {
            int y = __shfl_up(s, off, 4);
            if (t >= off) s += y;
        }
        wsum[t] = s;
    }
    __syncthreads();
    int bw = (wid > 0) ? wsum[wid - 1] : 0;
    int start = base + bw + x - v;
    int node = b * 256 + t;
    if (node < NN) {
        rowptr[node] = start;
        dinv[node] = rsqrtf((float)(v + 2));  // +2 self loops
    }
    __syncthreads();
    cnt[t] = start;
    __syncthreads();
    for (int i = base + t; i < endb; i += 256) {
        unsigned int u = part[i];
        int pos = atomicAdd(&cnt[u >> 16], 1);
        col[pos] = (int)(u & 0xFFFFu);
    }
    if (b == NB - 1 && t == 0) rowptr[NN] = NE;
}

// ---------------- agg1: 2 rows per wave, interleaved unroll-4 chains ----------------
__global__ void __launch_bounds__(256) agg1_csr(const int* __restrict__ rowptr, const int* __restrict__ col,
                                                const __half* __restrict__ hs1, const float* __restrict__ dinv,
                                                const float* __restrict__ b1, __half* __restrict__ h1h) {
    int t = threadIdx.x;
    int c2 = t & 63;
    int v0 = blockIdx.x * 8 + (t >> 6) * 2;   // NN/8 = 6250 blocks
    int v1 = v0 + 1;
    const __half2* H = (const __half2*)hs1;   // row stride 64
    int j0 = rowptr[v0], e0 = rowptr[v0 + 1];
    int j1 = rowptr[v1], e1 = rowptr[v1 + 1];
    float dv0 = dinv[v0], dv1 = dinv[v1];
    float2 sf0 = __half22float2(H[(size_t)v0 * 64 + c2]);
    float2 sf1 = __half22float2(H[(size_t)v1 * 64 + c2]);
    float ax0 = 2.f * dv0 * sf0.x, ay0 = 2.f * dv0 * sf0.y;
    float ax1 = 2.f * dv1 * sf1.x, ay1 = 2.f * dv1 * sf1.y;
    // interleaved main loop: 8 independent gathers in flight (4 per row)
    while (j0 + 4 <= e0 && j1 + 4 <= e1) {
        int a0 = col[j0], a1 = col[j0 + 1], a2 = col[j0 + 2], a3 = col[j0 + 3];
        int b0 = col[j1], b1_ = col[j1 + 1], b2 = col[j1 + 2], b3 = col[j1 + 3];
        float da0 = dinv[a0], da1 = dinv[a1], da2 = dinv[a2], da3 = dinv[a3];
        float db0 = dinv[b0], db1 = dinv[b1_], db2 = dinv[b2], db3 = dinv[b3];
        float2 va0 = __half22float2(H[(size_t)a0 * 64 + c2]);
        float2 va1 = __half22float2(H[(size_t)a1 * 64 + c2]);
        float2 va2 = __half22float2(H[(size_t)a2 * 64 + c2]);
        float2 va3 = __half22float2(H[(size_t)a3 * 64 + c2]);
        float2 vb0 = __half22float2(H[(size_t)b0 * 64 + c2]);
        float2 vb1 = __half22float2(H[(size_t)b1_ * 64 + c2]);
        float2 vb2 = __half22float2(H[(size_t)b2 * 64 + c2]);
        float2 vb3 = __half22float2(H[(size_t)b3 * 64 + c2]);
        ax0 += da0 * va0.x + da1 * va1.x + da2 * va2.x + da3 * va3.x;
        ay0 += da0 * va0.y + da1 * va1.y + da2 * va2.y + da3 * va3.y;
        ax1 += db0 * vb0.x + db1 * vb1.x + db2 * vb2.x + db3 * vb3.x;
        ay1 += db0 * vb0.y + db1 * vb1.y + db2 * vb2.y + db3 * vb3.y;
        j0 += 4; j1 += 4;
    }
    for (; j0 + 4 <= e0; j0 += 4) {
        int a0 = col[j0], a1 = col[j0 + 1], a2 = col[j0 + 2], a3 = col[j0 + 3];
        float da0 = dinv[a0], da1 = dinv[a1], da2 = dinv[a2], da3 = dinv[a3];
        float2 va0 = __half22float2(H[(size_t)a0 * 64 + c2]);
        float2 va1 = __half22float2(H[(size_t)a1 * 64 + c2]);
        float2 va2 = __half22float2(H[(size_t)a2 * 64 + c2]);
        float2 va3 = __half22float2(H[(size_t)a3 * 64 + c2]);
        ax0 += da0 * va0.x + da1 * va1.x + da2 * va2.x + da3 * va3.x;
        ay0 += da0 * va0.y + da1 * va1.y + da2 * va2.y + da3 * va3.y;
    }
    for (; j0 < e0; ++j0) {
        int s = col[j0];
        float ds = dinv[s];
        float2 u = __half22float2(H[(size_t)s * 64 + c2]);
        ax0 += ds * u.x; ay0 += ds * u.y;
    }
    for (; j1 + 4 <= e1; j1 += 4) {
        int b0 = col[j1], b1_ = col[j1 + 1], b2 = col[j1 + 2], b3 = col[j1 + 3];
        float db0 = dinv[b0], db1 = dinv[b1_], db2 = dinv[b2], db3 = dinv[b3];
        float2 vb0 = __half22float2(H[(size_t)b0 * 64 + c2]);
        float2 vb1 = __half22float2(H[(size_t)b1_ * 64 + c2]);
        float2 vb2 = __half22float2(H[(size_t)b2 * 64 + c2]);
        float2 vb3 = __half22float2(H[(size_t)b3 * 64 + c2]);
        ax1 += db0 * vb0.x + db1 * vb1.x + db2 * vb2.x + db3 * vb3.x;
        ay1 += db0 * vb0.y + db1 * vb1.y + db2 * vb2.y + db3 * vb3.y;
    }
    for (; j1 < e1; ++j1) {
        int s = col[j1];
        float ds = dinv[s];
        float2 u = __half22float2(H[(size_t)s * 64 + c2]);
        ax1 += ds * u.x; ay1 += ds * u.y;
    }
    int c = c2 * 2;
    float bx = b1[c], by = b1[c + 1];
    float r0x = fmaxf(dv0 * ax0 + bx, 0.f);
    float r0y = fmaxf(dv0 * ay0 + by, 0.f);
    float r1x = fmaxf(dv1 * ax1 + bx, 0.f);
    float r1y = fmaxf(dv1 * ay1 + by, 0.f);
    ((__half2*)h1h)[(size_t)v0 * 64 + c2] = __floats2half2_rn(r0x, r0y);
    ((__half2*)h1h)[(size_t)v1 * 64 + c2] = __floats2half2_rn(r1x, r1y);
}

// ---------------- GEMM2: hs2(fp16) = h1(fp16) @ W2 (unscaled) ----------------
__global__ void __launch_bounds__(256, 4) gemm2(const __half* __restrict__ h1h, const float* __restrict__ W2,
                                                __half* __restrict__ hs2) {
    __shared__ h2 w2[64 * 64];    // 16 KB
    __shared__ h2 xs2[64 * 66];   // 16.9 KB
    int t = threadIdx.x;
    int row0 = blockIdx.x * 64;
    const h2* H = (const h2*)h1h;
#pragma unroll
    for (int i = 0; i < 16; ++i) {
        int idx = t + 256 * i;
        int kp = idx >> 6, c = idx & 63;
        h2 v;
        v[0] = (_Float16)W2[(2 * kp) * CD + c];
        v[1] = (_Float16)W2[(2 * kp + 1) * CD + c];
        w2[idx] = v;
    }
#pragma unroll
    for (int i = 0; i < 16; ++i) {
        int idx = t + 256 * i;
        int r = idx >> 6, kp = idx & 63;
        int gr = row0 + r; if (gr > NN - 1) gr = NN - 1;
        xs2[r * 66 + kp] = H[(size_t)gr * 64 + kp];  // fp16 passthrough
    }
    __syncthreads();

    int lane = t & 63, wv_id = t >> 6;
    int cl = lane & 15, g = lane >> 4;
    int wrow = wv_id * 16 + g * 4;
    int ca = 4 * cl;

    float acc[4][4];
#pragma unroll
    for (int r = 0; r < 4; ++r)
#pragma unroll
        for (int c = 0; c < 4; ++c) acc[r][c] = 0.f;

#pragma unroll 2
    for (int kq = 0; kq < 32; ++kq) {
        H4 xv[4];
#pragma unroll
        for (int r = 0; r < 4; ++r)
            xv[r].v = *(const h4*)&xs2[(wrow + r) * 66 + 2 * kq];
        H8 wa0, wa1;
        wa0.v = *(const h8*)&w2[(2 * kq) * 64 + ca];
        wa1.v = *(const h8*)&w2[(2 * kq + 1) * 64 + ca];
#pragma unroll
        for (int r = 0; r < 4; ++r) {
            h2 x0 = xv[r].p[0];
            h2 x1 = xv[r].p[1];
#pragma unroll
            for (int cc = 0; cc < 4; ++cc) {
                acc[r][cc] = FDOT2(x0, wa0.p[cc], acc[r][cc]);
                acc[r][cc] = FDOT2(x1, wa1.p[cc], acc[r][cc]);
            }
        }
    }
#pragma unroll
    for (int rr = 0; rr < 4; ++rr) {
        int row = row0 + wrow + rr;
        if (row < NN) {
            union { __half2 h[2]; uint2 u; } p;
            p.h[0] = __floats2half2_rn(acc[rr][0], acc[rr][1]);
            p.h[1] = __floats2half2_rn(acc[rr][2], acc[rr][3]);
            *(uint2*)&hs2[(size_t)row * CD + ca] = p.u;
        }
    }
}

// ---------------- agg2: 2 rows per wave, interleaved; + bias + log_softmax ----------------
__global__ void __launch_bounds__(256) agg2_csr(const int* __restrict__ rowptr, const int* __restrict__ col,
                                                const __half* __restrict__ hs2, const float* __restrict__ dinv,
                                                const float* __restrict__ b2, float* __restrict__ out) {
    int t = threadIdx.x;
    int c = t & 63;
    int v0 = blockIdx.x * 8 + (t >> 6) * 2;
    int v1 = v0 + 1;
    int j0 = rowptr[v0], e0 = rowptr[v0 + 1];
    int j1 = rowptr[v1], e1 = rowptr[v1 + 1];
    float dv0 = dinv[v0], dv1 = dinv[v1];
    float acc0 = 2.f * dv0 * __half2float(hs2[(size_t)v0 * CD + c]);
    float acc1 = 2.f * dv1 * __half2float(hs2[(size_t)v1 * CD + c]);
    while (j0 + 4 <= e0 && j1 + 4 <= e1) {
        int a0 = col[j0], a1 = col[j0 + 1], a2 = col[j0 + 2], a3 = col[j0 + 3];
        int b0 = col[j1], b1_ = col[j1 + 1], b2_ = col[j1 + 2], b3 = col[j1 + 3];
        float da0 = dinv[a0], da1 = dinv[a1], da2 = dinv[a2], da3 = dinv[a3];
        float db0 = dinv[b0], db1 = dinv[b1_], db2 = dinv[b2_], db3 = dinv[b3];
        float fa0 = __half2float(hs2[(size_t)a0 * CD + c]), fa1 = __half2float(hs2[(size_t)a1 * CD + c]);
        float fa2 = __half2float(hs2[(size_t)a2 * CD + c]), fa3 = __half2float(hs2[(size_t)a3 * CD + c]);
        float fb0 = __half2float(hs2[(size_t)b0 * CD + c]), fb1 = __half2float(hs2[(size_t)b1_ * CD + c]);
        float fb2 = __half2float(hs2[(size_t)b2_ * CD + c]), fb3 = __half2float(hs2[(size_t)b3 * CD + c]);
        acc0 += da0 * fa0 + da1 * fa1 + da2 * fa2 + da3 * fa3;
        acc1 += db0 * fb0 + db1 * fb1 + db2 * fb2 + db3 * fb3;
        j0 += 4; j1 += 4;
    }
    for (; j0 + 4 <= e0; j0 += 4) {
        int a0 = col[j0], a1 = col[j0 + 1], a2 = col[j0 + 2], a3 = col[j0 + 3];
        float da0 = dinv[a0], da1 = dinv[a1], da2 = dinv[a2], da3 = dinv[a3];
        float fa0 = __half2float(hs2[(size_t)a0 * CD + c]), fa1 = __half2float(hs2[(size_t)a1 * CD + c]);
        float fa2 = __half2float(hs2[(size_t)a2 * CD + c]), fa3 = __half2float(hs2[(size_t)a3 * CD + c]);
        acc0 += da0 * fa0 + da1 * fa1 + da2 * fa2 + da3 * fa3;
    }
    for (; j0 < e0; ++j0) {
        int s = col[j0];
        acc0 += dinv[s] * __half2float(hs2[(size_t)s * CD + c]);
    }
    for (; j1 + 4 <= e1; j1 += 4) {
        int b0 = col[j1], b1_ = col[j1 + 1], b2_ = col[j1 + 2], b3 = col[j1 + 3];
        float db0 = dinv[b0], db1 = dinv[b1_], db2 = dinv[b2_], db3 = dinv[b3];
        float fb0 = __half2float(hs2[(size_t)b0 * CD + c]), fb1 = __half2float(hs2[(size_t)b1_ * CD + c]);
        float fb2 = __half2float(hs2[(size_t)b2_ * CD + c]), fb3 = __half2float(hs2[(size_t)b3 * CD + c]);
        acc1 += db0 * fb0 + db1 * fb1 + db2 * fb2 + db3 * fb3;
    }
    for (; j1 < e1; ++j1) {
        int s = col[j1];
        acc1 += dinv[s] * __half2float(hs2[(size_t)s * CD + c]);
    }
    float b2c = b2[c];
    // row v0 softmax
    float o0 = dv0 * acc0 + b2c;
    float m0 = o0;
#pragma unroll
    for (int off = 32; off >= 1; off >>= 1) m0 = fmaxf(m0, __shfl_xor(m0, off, 64));
    float ex0 = __expf(o0 - m0);
    float s0 = ex0;
#pragma unroll
    for (int off = 32; off >= 1; off >>= 1) s0 += __shfl_xor(s0, off, 64);
    out[(size_t)v0 * CD + c] = o0 - m0 - __logf(s0);
    // row v1 softmax
    float o1 = dv1 * acc1 + b2c;
    float m1 = o1;
#pragma unroll
    for (int off = 32; off >= 1; off >>= 1) m1 = fmaxf(m1, __shfl_xor(m1, off, 64));
    float ex1 = __expf(o1 - m1);
    float s1 = ex1;
#pragma unroll
    for (int off = 32; off >= 1; off >>= 1) s1 += __shfl_xor(s1, off, 64);
    out[(size_t)v1 * CD + c] = o1 - m1 - __logf(s1);
}

extern "C" void kernel_launch(void* const* d_in, const int* in_sizes, int n_in,
                              void* d_out, int out_size, void* d_ws, size_t ws_size,
                              hipStream_t stream) {
    const float* x  = (const float*)d_in[0];
    const int*   ei = (const int*)d_in[1];   // [2, E] int32
    const float* W1 = (const float*)d_in[2];
    const float* b1 = (const float*)d_in[3];
    const float* W2 = (const float*)d_in[4];
    const float* b2 = (const float*)d_in[5];
    float* out = (float*)d_out;

    const int* src = ei;
    const int* dst = ei + NE;

    float* ws = (float*)d_ws;
    float*        dinv    = ws;                              // NN floats
    int*          rowptr  = (int*)(ws + 65536);              // NN+1 ints
    int*          col     = (int*)(ws + 131072);             // NE ints -> 931072
    int*          cntMatT = (int*)(ws + 931136);             // NP ints
    int*          psums   = (int*)(ws + 956224);             // 25 ints
    unsigned int* part    = (unsigned int*)(ws + 960000);    // NE u32 -> 1760000
    __half*       hs1     = (__half*)(ws + 1760000);         // NN*HD halves -> 4960000
    __half*       h1h     = (__half*)(ws + 4960000);         // NN*HD halves -> 8160000
    __half*       hs2     = hs1;                             // reuse (hs1 dead after agg1)

    // 1) gemm1 (unscaled) fused with p1_hist
    gp1<<<G1B + BP, 256, 0, stream>>>(x, W1, hs1, dst, cntMatT);
    // 2) chunk-local scan of the (bucket,block) count matrix
    pscan_a<<<NPCHUNK, 1024, 0, stream>>>(cntMatT, psums);
    // 3) partition edges into bucket-major segments
    p3_scatter<<<BP, 256, 0, stream>>>(src, dst, cntMatT, psums, part);
    // 4) per-bucket CSR build (rowptr starts + dinv + col)
    fill2<<<NB, 256, 0, stream>>>(cntMatT, psums, part, rowptr, dinv, col);
    // 5) layer-1 aggregation (+ReLU), h1 in fp16; 2 rows/wave
    agg1_csr<<<NN / 8, 256, 0, stream>>>(rowptr, col, hs1, dinv, b1, h1h);
    // 6) layer-2 dense transform (fp16 in/out, unscaled)
    gemm2<<<(NN + 63) / 64, 256, 0, stream>>>(h1h, W2, hs2);
    // 7) layer-2 aggregation + bias + log_softmax; 2 rows/wave
    agg2_csr<<<NN / 8, 256, 0, stream>>>(rowptr, col, hs2, dinv, b2, out);
}